// Round 3
// baseline (2598.547 us; speedup 1.0000x reference)
//
#include <hip/hip_runtime.h>
#include <hip/hip_bf16.h>

#define DEV static __device__ __forceinline__

typedef __attribute__((ext_vector_type(8))) short bfx8;
typedef __attribute__((ext_vector_type(4))) float f32x4;
typedef __attribute__((ext_vector_type(4))) unsigned short us4;

DEV unsigned short f2bf(float f){
  unsigned u = __builtin_bit_cast(unsigned, f);
  u += 0x7fffu + ((u >> 16) & 1u);
  return (unsigned short)(u >> 16);
}
DEV float bf2f(unsigned short h){
  unsigned u = ((unsigned)h) << 16;
  return __builtin_bit_cast(float, u);
}
DEV void gld16(const void* g, void* l){
  __builtin_amdgcn_global_load_lds((const __attribute__((address_space(1))) void*)g,
                                   (__attribute__((address_space(3))) void*)l, 16, 0, 0);
}
DEV f32x4 mfma16(bfx8 a, bfx8 b, f32x4 c){
  return __builtin_amdgcn_mfma_f32_16x16x32_bf16(a, b, c, 0, 0, 0);
}

#define BAR() do{ asm volatile("" ::: "memory"); __builtin_amdgcn_s_barrier(); \
                  asm volatile("" ::: "memory"); }while(0)

// ---------------------------------------------------------------- weights ----
__global__ __launch_bounds__(256, 2)
void wconv_kernel(const float* __restrict__ attn_w, const float* __restrict__ ff_w1,
                  const float* __restrict__ ff_w2, const float* __restrict__ out1_w,
                  const float* __restrict__ out2_w,
                  unsigned short* __restrict__ bqkv, unsigned short* __restrict__ bout,
                  unsigned short* __restrict__ bff1, unsigned short* __restrict__ bff2,
                  unsigned short* __restrict__ bo1, unsigned short* __restrict__ bo2)
{
  __shared__ float ts[64][65];
  const int z = blockIdx.z;
  const float* src; unsigned short* dst; int K, N, stride;
  if (z < 48){
    int l = z / 12, br = (z % 12) >> 2, p = z & 3;
    src = attn_w + (size_t)z * 262144; K = 512; N = 512;
    if (p < 3){ dst = bqkv + (size_t)l * 4608 * 512 + (size_t)(br * 3 + p) * 262144; stride = 512; }
    else      { dst = bout + (size_t)l * 512 * 1536 + (size_t)br * 512;              stride = 1536; }
  } else if (z < 52){
    int l = z - 48; src = ff_w1 + (size_t)l * 524288; K = 512; N = 1024;
    dst = bff1 + (size_t)l * 524288; stride = 512;
  } else if (z < 56){
    int l = z - 52; src = ff_w2 + (size_t)l * 524288; K = 1024; N = 512;
    dst = bff2 + (size_t)l * 524288; stride = 1024;
  } else if (z == 56){
    src = out1_w; K = 512; N = 512; dst = bo1; stride = 512;
  } else {
    src = out2_w; K = 512; N = 256; dst = bo2; stride = 512;
  }
  const int n0 = blockIdx.x << 6, k0 = blockIdx.y << 6;
  if (n0 >= N || k0 >= K) return;
  const int tx = threadIdx.x & 63, ty = threadIdx.x >> 6;
  #pragma unroll
  for (int i = 0; i < 16; ++i){
    int row = (ty << 4) + i;
    ts[row][tx] = src[(size_t)(k0 + row) * N + n0 + tx];
  }
  __syncthreads();
  #pragma unroll
  for (int i = 0; i < 16; ++i){
    int row = (ty << 4) + i;
    dst[(size_t)(n0 + row) * stride + k0 + tx] = f2bf(ts[tx][row]);
  }
}

// ---------------------------------------------------------------- mask pack --
__global__ __launch_bounds__(256, 4)
void mpack_kernel(const int* __restrict__ m0, const int* __restrict__ m1,
                  const int* __restrict__ m2, unsigned long long* __restrict__ mp)
{
  const int row = (blockIdx.x << 2) + (threadIdx.x >> 6);
  const int lane = threadIdx.x & 63;
  const int* src = (row < 8192) ? (m0 + (size_t)row * 512)
                 : (row < 16384 ? (m1 + (size_t)(row - 8192) * 512)
                                : (m2 + (size_t)(row - 16384) * 512));
  #pragma unroll
  for (int c = 0; c < 8; ++c){
    const int v = src[(c << 6) + lane];
    const unsigned long long b = __ballot(v != 0);
    if (lane == c) mp[(size_t)row * 8 + c] = b;
  }
}

// ---------------------------------------------------------------- embed ------
// 8 tokens per block; weights read once per block (k-loop outer, token inner).
__global__ __launch_bounds__(256, 4)
void embed_kernel(const float* __restrict__ x, const float* __restrict__ cond,
                  const float* __restrict__ in_w, const float* __restrict__ in_b,
                  const float* __restrict__ cond_w, const float* __restrict__ cond_b,
                  float* __restrict__ h)
{
  __shared__ float xs[8][18];
  __shared__ float cs[8][89];
  const int m0 = blockIdx.x << 3;
  const int tid = threadIdx.x;
  for (int i = tid; i < 144; i += 256) xs[i / 18][i % 18] = x[(size_t)m0 * 18 + i];
  for (int i = tid; i < 712; i += 256) cs[i / 89][i % 89] = cond[(size_t)m0 * 89 + i];
  __syncthreads();
  #pragma unroll
  for (int hf = 0; hf < 2; ++hf){
    const int c = tid + (hf << 8);
    const float bsum = in_b[c] + cond_b[c];
    float a[8];
    #pragma unroll
    for (int mi = 0; mi < 8; ++mi) a[mi] = bsum;
    #pragma unroll
    for (int k = 0; k < 18; ++k){
      const float wv = in_w[k * 512 + c];
      #pragma unroll
      for (int mi = 0; mi < 8; ++mi) a[mi] += xs[mi][k] * wv;
    }
    for (int k = 0; k < 89; ++k){
      const float wv = cond_w[k * 512 + c];
      #pragma unroll
      for (int mi = 0; mi < 8; ++mi) a[mi] += cs[mi][k] * wv;
    }
    #pragma unroll
    for (int mi = 0; mi < 8; ++mi) h[(size_t)(m0 + mi) * 512 + c] = a[mi];
  }
}

// ---------------------------------------------------------------- inorm ------
__global__ __launch_bounds__(256, 4)
void inorm_kernel(const float* __restrict__ in, unsigned short* __restrict__ ob)
{
  const int wid = (blockIdx.x << 2) + (threadIdx.x >> 6);
  const int lane = threadIdx.x & 63;
  const float* row = in + (size_t)wid * 512;
  const float4 v0 = *(const float4*)(row + (lane << 2));
  const float4 v1 = *(const float4*)(row + 256 + (lane << 2));
  float s = v0.x + v0.y + v0.z + v0.w + v1.x + v1.y + v1.z + v1.w;
  float q = v0.x*v0.x + v0.y*v0.y + v0.z*v0.z + v0.w*v0.w
          + v1.x*v1.x + v1.y*v1.y + v1.z*v1.z + v1.w*v1.w;
  #pragma unroll
  for (int sh = 1; sh < 64; sh <<= 1){
    s += __shfl_xor(s, sh, 64);
    q += __shfl_xor(q, sh, 64);
  }
  const float mean = s * (1.f / 512.f);
  const float var = q * (1.f / 512.f) - mean * mean;
  const float rs = rsqrtf(var + 1e-5f);
  us4 o0, o1;
  o0[0] = f2bf((v0.x - mean) * rs); o0[1] = f2bf((v0.y - mean) * rs);
  o0[2] = f2bf((v0.z - mean) * rs); o0[3] = f2bf((v0.w - mean) * rs);
  o1[0] = f2bf((v1.x - mean) * rs); o1[1] = f2bf((v1.y - mean) * rs);
  o1[2] = f2bf((v1.z - mean) * rs); o1[3] = f2bf((v1.w - mean) * rs);
  *(us4*)(ob + (size_t)wid * 512 + (lane << 2)) = o0;
  *(us4*)(ob + (size_t)wid * 512 + 256 + (lane << 2)) = o1;
}

__global__ void f2b_kernel(const float* __restrict__ in, unsigned short* __restrict__ ob, int n)
{
  const int i = (blockIdx.x * 256 + threadIdx.x) << 2;
  if (i >= n) return;
  const float4 v = *(const float4*)(in + i);
  us4 o; o[0] = f2bf(v.x); o[1] = f2bf(v.y); o[2] = f2bf(v.z); o[3] = f2bf(v.w);
  *(us4*)(ob + i) = o;
}

// ---------------------------------------------------------------- GEMM 128 ---
// legacy m97-style kernel, kept only for small-N (out2, N=256)
template<int MODE>
__global__ __launch_bounds__(256, 2)
void gemm_bt(const unsigned short* __restrict__ A, const unsigned short* __restrict__ B,
             const float* __restrict__ bias, float* __restrict__ Cf,
             unsigned short* __restrict__ Cb, int M, int N, int K)
{
  __shared__ unsigned short As[128 * 64];
  __shared__ unsigned short Bs[128 * 64];
  const int tid = threadIdx.x;
  const int w = tid >> 6, lane = tid & 63;
  const int wm = w >> 1, wn = w & 1;
  const int lr = lane & 15, lh = lane >> 4;
  const int m0 = blockIdx.x << 7, n0 = blockIdx.y << 7;
  const int rA = lane >> 3;
  const int cA = (lane & 7) << 3;

  f32x4 acc[4][4];
  #pragma unroll
  for (int i = 0; i < 4; ++i)
    #pragma unroll
    for (int j = 0; j < 4; ++j) acc[i][j] = (f32x4)0.f;

  const int nkt = K >> 6;
  auto stage = [&](int kt){
    #pragma unroll
    for (int c = 0; c < 4; ++c){
      const int r = (c << 5) + (w << 3) + rA;
      gld16(A + (size_t)(m0 + r) * K + (kt << 6) + cA,
            (char*)As + ((c << 5) + (w << 3)) * 128);
      gld16(B + (size_t)(n0 + r) * K + (kt << 6) + cA,
            (char*)Bs + ((c << 5) + (w << 3)) * 128);
    }
  };
  stage(0);
  for (int kt = 0; kt < nkt; ++kt){
    __syncthreads();
    #pragma unroll
    for (int kk = 0; kk < 2; ++kk){
      bfx8 af[4], bg[4];
      #pragma unroll
      for (int i = 0; i < 4; ++i)
        af[i] = *(const bfx8*)(As + ((wm << 6) + (i << 4) + lr) * 64 + (kk << 5) + (lh << 3));
      #pragma unroll
      for (int j = 0; j < 4; ++j)
        bg[j] = *(const bfx8*)(Bs + ((wn << 6) + (j << 4) + lr) * 64 + (kk << 5) + (lh << 3));
      #pragma unroll
      for (int i = 0; i < 4; ++i)
        #pragma unroll
        for (int j = 0; j < 4; ++j)
          acc[i][j] = mfma16(af[i], bg[j], acc[i][j]);
    }
    __syncthreads();
    if (kt + 1 < nkt) stage(kt + 1);
  }
  #pragma unroll
  for (int i = 0; i < 4; ++i){
    const int row = m0 + (wm << 6) + (i << 4) + (lh << 2);
    #pragma unroll
    for (int j = 0; j < 4; ++j){
      const int col = n0 + (wn << 6) + (j << 4) + lr;
      const float bv = bias ? bias[col] : 0.f;
      #pragma unroll
      for (int r = 0; r < 4; ++r){
        float v = acc[i][j][r] + bv;
        if constexpr (MODE == 1){
          v = fmaxf(v, 0.f);
          Cb[(size_t)(row + r) * N + col] = f2bf(v);
        } else {
          Cf[(size_t)(row + r) * N + col] += v;
        }
      }
    }
  }
}

// ---------------------------------------------------------------- GEMM 256 ---
// 256x256 tile, BK=64 (two 32-wide K-halves), 8 waves (2Mx4N), 8-phase
// schedule with counted vmcnt(6), raw barriers, XOR-granule LDS swizzle,
// setprio around MFMA clusters. Requires M%256==0, N%256==0, K%128==0, K>=256.
// MODE 1: Cb = bf16(relu(acc+bias))  MODE 2: Cf += acc+bias
// MODE 3: QKV scatter (q/k standard, v transposed)
template<int MODE>
__global__ __launch_bounds__(512, 2)
void gemm256(const unsigned short* __restrict__ A, const unsigned short* __restrict__ B,
             const float* __restrict__ bias, float* __restrict__ Cf,
             unsigned short* __restrict__ Cb, unsigned short* __restrict__ qkp,
             unsigned short* __restrict__ vtp, int M, int N, int K)
{
  __shared__ unsigned short L[2][2][2][8192];  // [buf][A/B][khalf][256*32] = 128KB
  const int tid = threadIdx.x;
  const int w = tid >> 6, lane = tid & 63;
  const int wr = w >> 2, wc = w & 3;
  const int lr = lane & 15, lh = lane >> 4;

  // XCD swizzle (grid % 8 == 0 for all our shapes)
  const int nwg = gridDim.x;
  const int id = blockIdx.x;
  const int wg = (id & 7) * (nwg >> 3) + (id >> 3);
  const int mt = wg & 31, nt = wg >> 5;      // M == 8192 always
  const int m0 = mt << 8, n0 = nt << 8;

  f32x4 acc[8][4];
  #pragma unroll
  for (int f = 0; f < 8; ++f)
    #pragma unroll
    for (int n = 0; n < 4; ++n) acc[f][n] = (f32x4)0.f;

  // stage one K-half of one matrix: 2 block-wide gld16 (16KB)
  auto stage_half = [&](int buf, int kt, int kh, int mat){
    const unsigned short* G = mat ? B : A;
    const int base0 = mat ? n0 : m0;
    const int r0 = (w << 4) + (lane >> 2);
    const int ga = (lane & 3) ^ ((r0 >> 1) & 3);
    gld16(G + (size_t)(base0 + r0) * K + kt * 64 + kh * 32 + ga * 8,
          &L[buf][mat][kh][(w << 4) * 32]);
    gld16(G + (size_t)(base0 + 128 + r0) * K + kt * 64 + kh * 32 + ga * 8,
          &L[buf][mat][kh][(128 + (w << 4)) * 32]);
  };

  bfx8 af[8];
  auto loadA = [&](int buf, int kh){
    #pragma unroll
    for (int f = 0; f < 8; ++f){
      const int ra = wr * 128 + f * 16 + lr;
      af[f] = *(const bfx8*)&L[buf][0][kh][ra * 32 + ((lh ^ ((ra >> 1) & 3)) << 3)];
    }
  };
  auto ldB1 = [&](int buf, int kh, int g) -> bfx8 {
    const int rb = wc * 64 + g * 16 + lr;
    return *(const bfx8*)&L[buf][1][kh][rb * 32 + ((lh ^ ((rb >> 1) & 3)) << 3)];
  };
  auto mmaN = [&](int n, bfx8 b){
    __builtin_amdgcn_s_setprio(1);
    #pragma unroll
    for (int f = 0; f < 8; ++f) acc[f][n] = mfma16(af[f], b, acc[f][n]);
    __builtin_amdgcn_s_setprio(0);
  };

  const int nkt = K >> 6;
  const int niter = nkt >> 1;

  // prologue: FIFO order A-Ka(0),B-Ka(0),A-Kb(0),B-Kb(0),A-Ka(1),B-Ka(1),A-Kb(1)
  stage_half(0, 0, 0, 0); stage_half(0, 0, 0, 1);
  stage_half(0, 0, 1, 0); stage_half(0, 0, 1, 1);
  stage_half(1, 1, 0, 0); stage_half(1, 1, 0, 1);
  stage_half(1, 1, 1, 0);

  for (int i = 0; i < niter; ++i){
    const int t0 = 2 * i;
    const bool pre = (i + 1 < niter);
    bfx8 b0, b1;
    // P1 -------------------------------------------------- tile t0, Ka, n01
    asm volatile("s_waitcnt vmcnt(6)" ::: "memory");
    BAR();
    stage_half(1, t0 + 1, 1, 1);                 // B-Kb(t0+1)
    loadA(0, 0);
    b0 = ldB1(0, 0, 0); b1 = ldB1(0, 0, 1);
    mmaN(0, b0); mmaN(1, b1);
    // P2 -------------------------------------------------- tile t0, Ka, n23
    BAR();
    if (pre) stage_half(0, t0 + 2, 0, 0);        // A-Ka(t0+2)
    b0 = ldB1(0, 0, 2); b1 = ldB1(0, 0, 3);
    mmaN(2, b0); mmaN(3, b1);
    // P3 -------------------------------------------------- tile t0, Kb, n01
    BAR();
    if (pre) stage_half(0, t0 + 2, 0, 1);        // B-Ka(t0+2)
    loadA(0, 1);
    b0 = ldB1(0, 1, 0); b1 = ldB1(0, 1, 1);
    mmaN(0, b0); mmaN(1, b1);
    // P4 -------------------------------------------------- tile t0, Kb, n23
    BAR();
    if (pre) stage_half(0, t0 + 2, 1, 0);        // A-Kb(t0+2)
    b0 = ldB1(0, 1, 2); b1 = ldB1(0, 1, 3);
    mmaN(2, b0); mmaN(3, b1);
    // P5 -------------------------------------------------- tile t0+1, Ka, n01
    if (pre) asm volatile("s_waitcnt vmcnt(6)" ::: "memory");
    else     asm volatile("s_waitcnt vmcnt(0)" ::: "memory");
    BAR();
    if (pre) stage_half(0, t0 + 2, 1, 1);        // B-Kb(t0+2)
    loadA(1, 0);
    b0 = ldB1(1, 0, 0); b1 = ldB1(1, 0, 1);
    mmaN(0, b0); mmaN(1, b1);
    // P6 -------------------------------------------------- tile t0+1, Ka, n23
    BAR();
    if (pre) stage_half(1, t0 + 3, 0, 0);        // A-Ka(t0+3)
    b0 = ldB1(1, 0, 2); b1 = ldB1(1, 0, 3);
    mmaN(2, b0); mmaN(3, b1);
    // P7 -------------------------------------------------- tile t0+1, Kb, n01
    BAR();
    if (pre) stage_half(1, t0 + 3, 0, 1);        // B-Ka(t0+3)
    loadA(1, 1);
    b0 = ldB1(1, 1, 0); b1 = ldB1(1, 1, 1);
    mmaN(0, b0); mmaN(1, b1);
    // P8 -------------------------------------------------- tile t0+1, Kb, n23
    BAR();
    if (pre) stage_half(1, t0 + 3, 1, 0);        // A-Kb(t0+3)
    b0 = ldB1(1, 1, 2); b1 = ldB1(1, 1, 3);
    mmaN(2, b0); mmaN(3, b1);
  }

  // epilogue
  #pragma unroll
  for (int f = 0; f < 8; ++f){
    const int row = m0 + wr * 128 + f * 16 + (lh << 2);
    #pragma unroll
    for (int n = 0; n < 4; ++n){
      const int col = n0 + wc * 64 + n * 16 + lr;
      if constexpr (MODE == 1){
        const float bv = bias ? bias[col] : 0.f;
        #pragma unroll
        for (int r = 0; r < 4; ++r){
          float v = acc[f][n][r] + bv;
          v = fmaxf(v, 0.f);
          Cb[(size_t)(row + r) * N + col] = f2bf(v);
        }
      } else if constexpr (MODE == 2){
        const float bv = bias ? bias[col] : 0.f;
        #pragma unroll
        for (int r = 0; r < 4; ++r)
          Cf[(size_t)(row + r) * N + col] += acc[f][n][r] + bv;
      } else {
        const int br = col / 1536;
        const int rem = col - br * 1536;
        const int p = rem >> 9;
        const int c = rem & 511;
        const float bv = bias ? bias[(size_t)((br << 2) + p) * 512 + c] : 0.f;
        if (p < 2){
          #pragma unroll
          for (int r = 0; r < 4; ++r)
            qkp[((size_t)((br << 1) + p) * 8192 + row + r) * 512 + c] = f2bf(acc[f][n][r] + bv);
        } else {
          const int b_ = row >> 9, s0 = row & 511;
          const int hi = c >> 7, dk = c & 127;
          us4 pk;
          #pragma unroll
          for (int r = 0; r < 4; ++r) pk[r] = f2bf(acc[f][n][r] + bv);
          *(us4*)(vtp + (((size_t)(br * 16 + b_) * 4 + hi) * 128 + dk) * 512 + s0) = pk;
        }
      }
    }
  }
}

// ---------------------------------------------------------------- attention --
// Barrier-free: K and V fragments read directly from global (L2-resident);
// per-wave LDS for P relayout and packed masks (lgkmcnt-fenced, wave-local).
__global__ __launch_bounds__(256, 2)
void attn_kernel(const unsigned short* __restrict__ qk, const unsigned short* __restrict__ vt,
                 const unsigned* __restrict__ mp, unsigned short* __restrict__ outp)
{
  __shared__ unsigned short Pl[4][16 * 40];
  __shared__ unsigned Mk[4][16 * 17];
  const int tid = threadIdx.x;
  const int w = tid >> 6, lane = tid & 63;
  const int lr = lane & 15, lh = lane >> 4;
  const int id = blockIdx.x;
  const int pair = (id & 7) * 24 + (id >> 6);
  const int qt = (id >> 3) & 7;
  const int br = pair >> 6, bh = pair & 63;
  const int b = bh >> 2, h = bh & 3;
  const int q0 = (qt << 6) + (w << 4);

  const unsigned short* qbase = qk + ((size_t)(br * 2 + 0) * 8192 + (size_t)b * 512) * 512 + h * 128;
  const unsigned short* kbase = qk + ((size_t)(br * 2 + 1) * 8192 + (size_t)b * 512) * 512 + h * 128;
  const unsigned short* vbase = vt + ((size_t)(br * 16 + b) * 4 + h) * 128 * 512;
  const unsigned* mrow = mp + ((size_t)br * 8192 + (size_t)b * 512 + (qt << 6) + (w << 4)) * 16;

  // wave-local packed-mask fill: 16 rows x 16 words
  unsigned* mk = Mk[w];
  #pragma unroll
  for (int u = 0; u < 4; ++u){
    const int idx = (lane << 2) + u;
    const int rw = idx >> 4, wd = idx & 15;
    mk[rw * 17 + wd] = mrow[rw * 16 + wd];
  }
  asm volatile("s_waitcnt lgkmcnt(0)" ::: "memory");

  bfx8 aq[4];
  #pragma unroll
  for (int t = 0; t < 4; ++t)
    aq[t] = *(const bfx8*)(qbase + (size_t)(q0 + lr) * 512 + (t << 5) + (lh << 3));

  f32x4 sc[16][2];
  const float scale = 0.08838834764831845f;  // 1/sqrt(128)

  // phase 1: scores = QK^T directly from global K
  #pragma unroll 4
  for (int kt = 0; kt < 16; ++kt){
    #pragma unroll
    for (int j = 0; j < 2; ++j){
      const int rk = (kt << 5) + (j << 4) + lr;
      f32x4 a2 = (f32x4)0.f;
      __builtin_amdgcn_s_setprio(1);
      #pragma unroll
      for (int t = 0; t < 4; ++t){
        bfx8 bk = *(const bfx8*)(kbase + (size_t)rk * 512 + (t << 5) + (lh << 3));
        a2 = mfma16(aq[t], bk, a2);
      }
      __builtin_amdgcn_s_setprio(0);
      #pragma unroll
      for (int r = 0; r < 4; ++r){
        const unsigned mword = mk[((lh << 2) + r) * 17 + kt];
        const int bit = (mword >> ((j << 4) + lr)) & 1;
        sc[kt][j][r] = bit ? -1e9f : a2[r] * scale;
      }
    }
  }

  // phase 2: wave-parallel softmax
  float mx[4] = {-3e38f, -3e38f, -3e38f, -3e38f};
  #pragma unroll
  for (int kt = 0; kt < 16; ++kt)
    #pragma unroll
    for (int j = 0; j < 2; ++j)
      #pragma unroll
      for (int r = 0; r < 4; ++r) mx[r] = fmaxf(mx[r], sc[kt][j][r]);
  #pragma unroll
  for (int s = 1; s < 16; s <<= 1)
    #pragma unroll
    for (int r = 0; r < 4; ++r) mx[r] = fmaxf(mx[r], __shfl_xor(mx[r], s, 64));
  float sm[4] = {0.f, 0.f, 0.f, 0.f};
  #pragma unroll
  for (int kt = 0; kt < 16; ++kt)
    #pragma unroll
    for (int j = 0; j < 2; ++j)
      #pragma unroll
      for (int r = 0; r < 4; ++r){
        const float pv = __expf(sc[kt][j][r] - mx[r]);
        sc[kt][j][r] = pv;
        sm[r] += pv;
      }
  #pragma unroll
  for (int s = 1; s < 16; s <<= 1)
    #pragma unroll
    for (int r = 0; r < 4; ++r) sm[r] += __shfl_xor(sm[r], s, 64);
  float linv[4];
  #pragma unroll
  for (int r = 0; r < 4; ++r) linv[r] = 1.f / sm[r];

  // phase 3: O = P*V, V fragments from global; P relayout via wave-local LDS
  f32x4 ao[8];
  #pragma unroll
  for (int j = 0; j < 8; ++j) ao[j] = (f32x4)0.f;
  unsigned short* pw = Pl[w];
  #pragma unroll 2
  for (int kt = 0; kt < 16; ++kt){
    #pragma unroll
    for (int j = 0; j < 2; ++j)
      #pragma unroll
      for (int r = 0; r < 4; ++r)
        pw[((lh << 2) + r) * 40 + (j << 4) + lr] = f2bf(sc[kt][j][r] * linv[r]);
    asm volatile("s_waitcnt lgkmcnt(0)" ::: "memory");
    bfx8 pa = *(const bfx8*)(pw + lr * 40 + (lh << 3));
    __builtin_amdgcn_s_setprio(1);
    #pragma unroll
    for (int j = 0; j < 8; ++j){
      bfx8 bv = *(const bfx8*)(vbase + (size_t)((j << 4) + lr) * 512 + (kt << 5) + (lh << 3));
      ao[j] = mfma16(pa, bv, ao[j]);
    }
    __builtin_amdgcn_s_setprio(0);
    asm volatile("" ::: "memory");
  }
  const size_t obase = (size_t)(b * 512) * 1536 + br * 512 + h * 128;
  #pragma unroll
  for (int j = 0; j < 8; ++j){
    const int d = (j << 4) + lr;
    #pragma unroll
    for (int r = 0; r < 4; ++r){
      const int q = q0 + (lh << 2) + r;
      outp[obase + (size_t)q * 1536 + d] = f2bf(ao[j][r]);
    }
  }
}

// ---------------------------------------------------------------- out3 -------
__global__ __launch_bounds__(256, 4)
void out3_kernel(const unsigned short* __restrict__ t2, const float* __restrict__ w,
                 const float* __restrict__ b2, float* __restrict__ outp)
{
  const int row = (blockIdx.x << 2) + (threadIdx.x >> 6);
  const int lane = threadIdx.x & 63;
  const unsigned short* rp = t2 + (size_t)row * 256 + (lane << 2);
  float a0 = 0.f, a1 = 0.f;
  #pragma unroll
  for (int k = 0; k < 4; ++k){
    const float v = bf2f(rp[k]);
    const int kk = (lane << 2) + k;
    a0 += v * w[kk * 2 + 0];
    a1 += v * w[kk * 2 + 1];
  }
  #pragma unroll
  for (int s = 1; s < 64; s <<= 1){
    a0 += __shfl_xor(a0, s, 64);
    a1 += __shfl_xor(a1, s, 64);
  }
  if (lane == 0){
    outp[(size_t)row * 2 + 0] = a0 + b2[0];
    outp[(size_t)row * 2 + 1] = a1 + b2[1];
  }
}

// ---------------------------------------------------------------- launch -----
extern "C" void kernel_launch(void* const* d_in, const int* in_sizes, int n_in,
                              void* d_out, int out_size, void* d_ws, size_t ws_size,
                              hipStream_t stream)
{
  const float* x      = (const float*)d_in[0];
  const float* cond   = (const float*)d_in[1];
  const int*   mdoor  = (const int*)d_in[2];
  const int*   mself  = (const int*)d_in[3];
  const int*   mgen   = (const int*)d_in[4];
  const float* attn_w = (const float*)d_in[5];
  const float* attn_b = (const float*)d_in[6];
  const float* ff_w1  = (const float*)d_in[7];
  const float* ff_b1  = (const float*)d_in[8];
  const float* ff_w2  = (const float*)d_in[9];
  const float* ff_b2  = (const float*)d_in[10];
  const float* in_w   = (const float*)d_in[11];
  const float* in_b   = (const float*)d_in[12];
  const float* cond_w = (const float*)d_in[13];
  const float* cond_b = (const float*)d_in[14];
  const float* out1_w = (const float*)d_in[15];
  const float* out1_b = (const float*)d_in[16];
  const float* out2_w = (const float*)d_in[17];
  const float* out2_b = (const float*)d_in[18];
  const float* out3_w = (const float*)d_in[19];
  const float* out3_b = (const float*)d_in[20];

  char* p = (char*)d_ws;
  auto carve = [&](size_t bytes) -> char* {
    char* r = p; p += (bytes + 255) & ~(size_t)255; return r;
  };
  float*          h    = (float*)carve(8192ull * 512 * 4);
  unsigned short* h2   = (unsigned short*)carve(8192ull * 512 * 2);
  unsigned short* bqkv = (unsigned short*)carve(4ull * 4608 * 512 * 2);
  unsigned short* bout = (unsigned short*)carve(4ull * 512 * 1536 * 2);
  unsigned short* bff1 = (unsigned short*)carve(4ull * 1024 * 512 * 2);
  unsigned short* bff2 = (unsigned short*)carve(4ull * 512 * 1024 * 2);
  unsigned short* bo1  = (unsigned short*)carve(512ull * 512 * 2);
  unsigned short* bo2  = (unsigned short*)carve(256ull * 512 * 2);
  unsigned short* qkb  = (unsigned short*)carve(6ull * 8192 * 512 * 2);
  unsigned short* vtb  = (unsigned short*)carve(3ull * 16 * 4 * 128 * 512 * 2);
  unsigned short* att  = (unsigned short*)carve(8192ull * 1536 * 2);
  unsigned short* t    = (unsigned short*)carve(8192ull * 1024 * 2);
  unsigned short* t2   = (unsigned short*)carve(8192ull * 256 * 2);
  unsigned long long* mpk = (unsigned long long*)carve(24576ull * 8 * 8);
  float* outf = (float*)d_out;

  wconv_kernel<<<dim3(16, 16, 58), 256, 0, stream>>>(attn_w, ff_w1, ff_w2, out1_w, out2_w,
                                                     bqkv, bout, bff1, bff2, bo1, bo2);
  mpack_kernel<<<dim3(6144), 256, 0, stream>>>(mdoor, mself, mgen, mpk);
  embed_kernel<<<dim3(1024), 256, 0, stream>>>(x, cond, in_w, in_b, cond_w, cond_b, h);
  for (int l = 0; l < 4; ++l){
    inorm_kernel<<<dim3(2048), 256, 0, stream>>>(h, h2);
    gemm256<3><<<dim3(576), 512, 0, stream>>>(h2, bqkv + (size_t)l * 4608 * 512,
        attn_b + (size_t)l * 6144, nullptr, nullptr, qkb, vtb, 8192, 4608, 512);
    attn_kernel<<<dim3(1536), 256, 0, stream>>>(qkb, vtb, (const unsigned*)mpk, att);
    gemm256<2><<<dim3(64), 512, 0, stream>>>(att, bout + (size_t)l * 512 * 1536,
        nullptr, h, nullptr, nullptr, nullptr, 8192, 512, 1536);
    inorm_kernel<<<dim3(2048), 256, 0, stream>>>(h, h2);
    gemm256<1><<<dim3(128), 512, 0, stream>>>(h2, bff1 + (size_t)l * 1024 * 512,
        ff_b1 + (size_t)l * 1024, nullptr, t, nullptr, nullptr, 8192, 1024, 512);
    gemm256<2><<<dim3(64), 512, 0, stream>>>(t, bff2 + (size_t)l * 512 * 1024,
        ff_b2 + (size_t)l * 512, h, nullptr, nullptr, nullptr, 8192, 512, 1024);
  }
  f2b_kernel<<<dim3(4096), 256, 0, stream>>>(h, h2, 8192 * 512);
  gemm256<1><<<dim3(64), 512, 0, stream>>>(h2, bo1, out1_b, nullptr, att, nullptr, nullptr, 8192, 512, 512);
  gemm_bt<1><<<dim3(64, 2), 256, 0, stream>>>(att, bo2, out2_b, nullptr, t2, 8192, 256, 512);
  out3_kernel<<<dim3(2048), 256, 0, stream>>>(t2, out3_w, out3_b, outf);
}

// Round 4
// 1735.995 us; speedup vs baseline: 1.4969x; 1.4969x over previous
//
#include <hip/hip_runtime.h>
#include <hip/hip_bf16.h>

#define DEV static __device__ __forceinline__

typedef __attribute__((ext_vector_type(8))) short bfx8;
typedef __attribute__((ext_vector_type(4))) float f32x4;
typedef __attribute__((ext_vector_type(4))) unsigned short us4;

DEV unsigned short f2bf(float f){
  unsigned u = __builtin_bit_cast(unsigned, f);
  u += 0x7fffu + ((u >> 16) & 1u);
  return (unsigned short)(u >> 16);
}
DEV float bf2f(unsigned short h){
  unsigned u = ((unsigned)h) << 16;
  return __builtin_bit_cast(float, u);
}
DEV void gld16(const void* g, void* l){
  __builtin_amdgcn_global_load_lds((const __attribute__((address_space(1))) void*)g,
                                   (__attribute__((address_space(3))) void*)l, 16, 0, 0);
}
DEV f32x4 mfma16(bfx8 a, bfx8 b, f32x4 c){
  return __builtin_amdgcn_mfma_f32_16x16x32_bf16(a, b, c, 0, 0, 0);
}

#define BAR() do{ asm volatile("" ::: "memory"); __builtin_amdgcn_s_barrier(); \
                  asm volatile("" ::: "memory"); }while(0)

// ---------------------------------------------------------------- weights ----
__global__ __launch_bounds__(256, 2)
void wconv_kernel(const float* __restrict__ attn_w, const float* __restrict__ ff_w1,
                  const float* __restrict__ ff_w2, const float* __restrict__ out1_w,
                  const float* __restrict__ out2_w,
                  unsigned short* __restrict__ bqkv, unsigned short* __restrict__ bout,
                  unsigned short* __restrict__ bff1, unsigned short* __restrict__ bff2,
                  unsigned short* __restrict__ bo1, unsigned short* __restrict__ bo2)
{
  __shared__ float ts[64][65];
  const int z = blockIdx.z;
  const float* src; unsigned short* dst; int K, N, stride;
  if (z < 48){
    int l = z / 12, br = (z % 12) >> 2, p = z & 3;
    src = attn_w + (size_t)z * 262144; K = 512; N = 512;
    if (p < 3){ dst = bqkv + (size_t)l * 4608 * 512 + (size_t)(br * 3 + p) * 262144; stride = 512; }
    else      { dst = bout + (size_t)l * 512 * 1536 + (size_t)br * 512;              stride = 1536; }
  } else if (z < 52){
    int l = z - 48; src = ff_w1 + (size_t)l * 524288; K = 512; N = 1024;
    dst = bff1 + (size_t)l * 524288; stride = 512;
  } else if (z < 56){
    int l = z - 52; src = ff_w2 + (size_t)l * 524288; K = 1024; N = 512;
    dst = bff2 + (size_t)l * 524288; stride = 1024;
  } else if (z == 56){
    src = out1_w; K = 512; N = 512; dst = bo1; stride = 512;
  } else {
    src = out2_w; K = 512; N = 256; dst = bo2; stride = 512;
  }
  const int n0 = blockIdx.x << 6, k0 = blockIdx.y << 6;
  if (n0 >= N || k0 >= K) return;
  const int tx = threadIdx.x & 63, ty = threadIdx.x >> 6;
  #pragma unroll
  for (int i = 0; i < 16; ++i){
    int row = (ty << 4) + i;
    ts[row][tx] = src[(size_t)(k0 + row) * N + n0 + tx];
  }
  __syncthreads();
  #pragma unroll
  for (int i = 0; i < 16; ++i){
    int row = (ty << 4) + i;
    dst[(size_t)(n0 + row) * stride + k0 + tx] = f2bf(ts[tx][row]);
  }
}

// ---------------------------------------------------------------- mask pack --
__global__ __launch_bounds__(256, 4)
void mpack_kernel(const int* __restrict__ m0, const int* __restrict__ m1,
                  const int* __restrict__ m2, unsigned long long* __restrict__ mp)
{
  const int row = (blockIdx.x << 2) + (threadIdx.x >> 6);
  const int lane = threadIdx.x & 63;
  const int* src = (row < 8192) ? (m0 + (size_t)row * 512)
                 : (row < 16384 ? (m1 + (size_t)(row - 8192) * 512)
                                : (m2 + (size_t)(row - 16384) * 512));
  #pragma unroll
  for (int c = 0; c < 8; ++c){
    const int v = src[(c << 6) + lane];
    const unsigned long long b = __ballot(v != 0);
    if (lane == c) mp[(size_t)row * 8 + c] = b;
  }
}

// ---------------------------------------------------------------- embed ------
__global__ __launch_bounds__(256, 4)
void embed_kernel(const float* __restrict__ x, const float* __restrict__ cond,
                  const float* __restrict__ in_w, const float* __restrict__ in_b,
                  const float* __restrict__ cond_w, const float* __restrict__ cond_b,
                  float* __restrict__ h)
{
  __shared__ float xs[8][18];
  __shared__ float cs[8][89];
  const int m0 = blockIdx.x << 3;
  const int tid = threadIdx.x;
  for (int i = tid; i < 144; i += 256) xs[i / 18][i % 18] = x[(size_t)m0 * 18 + i];
  for (int i = tid; i < 712; i += 256) cs[i / 89][i % 89] = cond[(size_t)m0 * 89 + i];
  __syncthreads();
  #pragma unroll
  for (int hf = 0; hf < 2; ++hf){
    const int c = tid + (hf << 8);
    const float bsum = in_b[c] + cond_b[c];
    float a[8];
    #pragma unroll
    for (int mi = 0; mi < 8; ++mi) a[mi] = bsum;
    #pragma unroll
    for (int k = 0; k < 18; ++k){
      const float wv = in_w[k * 512 + c];
      #pragma unroll
      for (int mi = 0; mi < 8; ++mi) a[mi] += xs[mi][k] * wv;
    }
    for (int k = 0; k < 89; ++k){
      const float wv = cond_w[k * 512 + c];
      #pragma unroll
      for (int mi = 0; mi < 8; ++mi) a[mi] += cs[mi][k] * wv;
    }
    #pragma unroll
    for (int mi = 0; mi < 8; ++mi) h[(size_t)(m0 + mi) * 512 + c] = a[mi];
  }
}

// ---------------------------------------------------------------- inorm ------
__global__ __launch_bounds__(256, 4)
void inorm_kernel(const float* __restrict__ in, unsigned short* __restrict__ ob)
{
  const int wid = (blockIdx.x << 2) + (threadIdx.x >> 6);
  const int lane = threadIdx.x & 63;
  const float* row = in + (size_t)wid * 512;
  const float4 v0 = *(const float4*)(row + (lane << 2));
  const float4 v1 = *(const float4*)(row + 256 + (lane << 2));
  float s = v0.x + v0.y + v0.z + v0.w + v1.x + v1.y + v1.z + v1.w;
  float q = v0.x*v0.x + v0.y*v0.y + v0.z*v0.z + v0.w*v0.w
          + v1.x*v1.x + v1.y*v1.y + v1.z*v1.z + v1.w*v1.w;
  #pragma unroll
  for (int sh = 1; sh < 64; sh <<= 1){
    s += __shfl_xor(s, sh, 64);
    q += __shfl_xor(q, sh, 64);
  }
  const float mean = s * (1.f / 512.f);
  const float var = q * (1.f / 512.f) - mean * mean;
  const float rs = rsqrtf(var + 1e-5f);
  us4 o0, o1;
  o0[0] = f2bf((v0.x - mean) * rs); o0[1] = f2bf((v0.y - mean) * rs);
  o0[2] = f2bf((v0.z - mean) * rs); o0[3] = f2bf((v0.w - mean) * rs);
  o1[0] = f2bf((v1.x - mean) * rs); o1[1] = f2bf((v1.y - mean) * rs);
  o1[2] = f2bf((v1.z - mean) * rs); o1[3] = f2bf((v1.w - mean) * rs);
  *(us4*)(ob + (size_t)wid * 512 + (lane << 2)) = o0;
  *(us4*)(ob + (size_t)wid * 512 + 256 + (lane << 2)) = o1;
}

__global__ void f2b_kernel(const float* __restrict__ in, unsigned short* __restrict__ ob, int n)
{
  const int i = (blockIdx.x * 256 + threadIdx.x) << 2;
  if (i >= n) return;
  const float4 v = *(const float4*)(in + i);
  us4 o; o[0] = f2bf(v.x); o[1] = f2bf(v.y); o[2] = f2bf(v.z); o[3] = f2bf(v.w);
  *(us4*)(ob + i) = o;
}

// ---------------------------------------------------------------- GEMM 128 ---
// m97-style 128x128 kernel for the small-N GEMMs (enough workgroups).
template<int MODE>
__global__ __launch_bounds__(256, 2)
void gemm_bt(const unsigned short* __restrict__ A, const unsigned short* __restrict__ B,
             const float* __restrict__ bias, float* __restrict__ Cf,
             unsigned short* __restrict__ Cb, int M, int N, int K)
{
  __shared__ unsigned short As[128 * 64];
  __shared__ unsigned short Bs[128 * 64];
  const int tid = threadIdx.x;
  const int w = tid >> 6, lane = tid & 63;
  const int wm = w >> 1, wn = w & 1;
  const int lr = lane & 15, lh = lane >> 4;
  const int m0 = blockIdx.x << 7, n0 = blockIdx.y << 7;
  const int rA = lane >> 3;
  const int cA = (lane & 7) << 3;

  f32x4 acc[4][4];
  #pragma unroll
  for (int i = 0; i < 4; ++i)
    #pragma unroll
    for (int j = 0; j < 4; ++j) acc[i][j] = (f32x4)0.f;

  const int nkt = K >> 6;
  auto stage = [&](int kt){
    #pragma unroll
    for (int c = 0; c < 4; ++c){
      const int r = (c << 5) + (w << 3) + rA;
      gld16(A + (size_t)(m0 + r) * K + (kt << 6) + cA,
            (char*)As + ((c << 5) + (w << 3)) * 128);
      gld16(B + (size_t)(n0 + r) * K + (kt << 6) + cA,
            (char*)Bs + ((c << 5) + (w << 3)) * 128);
    }
  };
  stage(0);
  for (int kt = 0; kt < nkt; ++kt){
    __syncthreads();
    #pragma unroll
    for (int kk = 0; kk < 2; ++kk){
      bfx8 af[4], bg[4];
      #pragma unroll
      for (int i = 0; i < 4; ++i)
        af[i] = *(const bfx8*)(As + ((wm << 6) + (i << 4) + lr) * 64 + (kk << 5) + (lh << 3));
      #pragma unroll
      for (int j = 0; j < 4; ++j)
        bg[j] = *(const bfx8*)(Bs + ((wn << 6) + (j << 4) + lr) * 64 + (kk << 5) + (lh << 3));
      #pragma unroll
      for (int i = 0; i < 4; ++i)
        #pragma unroll
        for (int j = 0; j < 4; ++j)
          acc[i][j] = mfma16(af[i], bg[j], acc[i][j]);
    }
    __syncthreads();
    if (kt + 1 < nkt) stage(kt + 1);
  }
  #pragma unroll
  for (int i = 0; i < 4; ++i){
    const int row = m0 + (wm << 6) + (i << 4) + (lh << 2);
    #pragma unroll
    for (int j = 0; j < 4; ++j){
      const int col = n0 + (wn << 6) + (j << 4) + lr;
      const float bv = bias ? bias[col] : 0.f;
      #pragma unroll
      for (int r = 0; r < 4; ++r){
        float v = acc[i][j][r] + bv;
        if constexpr (MODE == 1){
          v = fmaxf(v, 0.f);
          Cb[(size_t)(row + r) * N + col] = f2bf(v);
        } else {
          Cf[(size_t)(row + r) * N + col] += v;
        }
      }
    }
  }
}

// ---------------------------------------------------------------- GEMM 256 ---
// 256x256 tile, 8-phase counted-vmcnt schedule. Used ONLY for QKV (576 wgs).
__global__ __launch_bounds__(512, 2)
void gemm256_qkv(const unsigned short* __restrict__ A, const unsigned short* __restrict__ B,
                 const float* __restrict__ bias, unsigned short* __restrict__ qkp,
                 unsigned short* __restrict__ vtp, int K)
{
  __shared__ unsigned short L[2][2][2][8192];  // [buf][A/B][khalf][256*32] = 128KB
  const int tid = threadIdx.x;
  const int w = tid >> 6, lane = tid & 63;
  const int wr = w >> 2, wc = w & 3;
  const int lr = lane & 15, lh = lane >> 4;

  const int nwg = gridDim.x;
  const int id = blockIdx.x;
  const int wg = (id & 7) * (nwg >> 3) + (id >> 3);
  const int mt = wg & 31, nt = wg >> 5;
  const int m0 = mt << 8, n0 = nt << 8;

  f32x4 acc[8][4];
  #pragma unroll
  for (int f = 0; f < 8; ++f)
    #pragma unroll
    for (int n = 0; n < 4; ++n) acc[f][n] = (f32x4)0.f;

  auto stage_half = [&](int buf, int kt, int kh, int mat){
    const unsigned short* G = mat ? B : A;
    const int base0 = mat ? n0 : m0;
    const int r0 = (w << 4) + (lane >> 2);
    const int ga = (lane & 3) ^ ((r0 >> 1) & 3);
    gld16(G + (size_t)(base0 + r0) * K + kt * 64 + kh * 32 + ga * 8,
          &L[buf][mat][kh][(w << 4) * 32]);
    gld16(G + (size_t)(base0 + 128 + r0) * K + kt * 64 + kh * 32 + ga * 8,
          &L[buf][mat][kh][(128 + (w << 4)) * 32]);
  };

  bfx8 af[8];
  auto loadA = [&](int buf, int kh){
    #pragma unroll
    for (int f = 0; f < 8; ++f){
      const int ra = wr * 128 + f * 16 + lr;
      af[f] = *(const bfx8*)&L[buf][0][kh][ra * 32 + ((lh ^ ((ra >> 1) & 3)) << 3)];
    }
  };
  auto ldB1 = [&](int buf, int kh, int g) -> bfx8 {
    const int rb = wc * 64 + g * 16 + lr;
    return *(const bfx8*)&L[buf][1][kh][rb * 32 + ((lh ^ ((rb >> 1) & 3)) << 3)];
  };
  auto mmaN = [&](int n, bfx8 b){
    __builtin_amdgcn_s_setprio(1);
    #pragma unroll
    for (int f = 0; f < 8; ++f) acc[f][n] = mfma16(af[f], b, acc[f][n]);
    __builtin_amdgcn_s_setprio(0);
  };

  const int niter = K >> 7;

  stage_half(0, 0, 0, 0); stage_half(0, 0, 0, 1);
  stage_half(0, 0, 1, 0); stage_half(0, 0, 1, 1);
  stage_half(1, 1, 0, 0); stage_half(1, 1, 0, 1);
  stage_half(1, 1, 1, 0);

  for (int i = 0; i < niter; ++i){
    const int t0 = 2 * i;
    const bool pre = (i + 1 < niter);
    bfx8 b0, b1;
    asm volatile("s_waitcnt vmcnt(6)" ::: "memory");
    BAR();
    stage_half(1, t0 + 1, 1, 1);
    loadA(0, 0);
    b0 = ldB1(0, 0, 0); b1 = ldB1(0, 0, 1);
    mmaN(0, b0); mmaN(1, b1);
    BAR();
    if (pre) stage_half(0, t0 + 2, 0, 0);
    b0 = ldB1(0, 0, 2); b1 = ldB1(0, 0, 3);
    mmaN(2, b0); mmaN(3, b1);
    BAR();
    if (pre) stage_half(0, t0 + 2, 0, 1);
    loadA(0, 1);
    b0 = ldB1(0, 1, 0); b1 = ldB1(0, 1, 1);
    mmaN(0, b0); mmaN(1, b1);
    BAR();
    if (pre) stage_half(0, t0 + 2, 1, 0);
    b0 = ldB1(0, 1, 2); b1 = ldB1(0, 1, 3);
    mmaN(2, b0); mmaN(3, b1);
    if (pre) asm volatile("s_waitcnt vmcnt(6)" ::: "memory");
    else     asm volatile("s_waitcnt vmcnt(0)" ::: "memory");
    BAR();
    if (pre) stage_half(0, t0 + 2, 1, 1);
    loadA(1, 0);
    b0 = ldB1(1, 0, 0); b1 = ldB1(1, 0, 1);
    mmaN(0, b0); mmaN(1, b1);
    BAR();
    if (pre) stage_half(1, t0 + 3, 0, 0);
    b0 = ldB1(1, 0, 2); b1 = ldB1(1, 0, 3);
    mmaN(2, b0); mmaN(3, b1);
    BAR();
    if (pre) stage_half(1, t0 + 3, 0, 1);
    loadA(1, 1);
    b0 = ldB1(1, 1, 0); b1 = ldB1(1, 1, 1);
    mmaN(0, b0); mmaN(1, b1);
    BAR();
    if (pre) stage_half(1, t0 + 3, 1, 0);
    b0 = ldB1(1, 1, 2); b1 = ldB1(1, 1, 3);
    mmaN(2, b0); mmaN(3, b1);
  }

  // epilogue: QKV scatter (q/k standard layout, v transposed [br][b][h][dk][s])
  #pragma unroll
  for (int f = 0; f < 8; ++f){
    const int row = wr * 128 + f * 16 + (lh << 2);  // local; m0 added below
    #pragma unroll
    for (int n = 0; n < 4; ++n){
      const int col = n0 + wc * 64 + n * 16 + lr;
      const int br = col / 1536;
      const int rem = col - br * 1536;
      const int p = rem >> 9;
      const int c = rem & 511;
      const float bv = bias ? bias[(size_t)((br << 2) + p) * 512 + c] : 0.f;
      const int grow = m0 + row;
      if (p < 2){
        #pragma unroll
        for (int r = 0; r < 4; ++r)
          qkp[((size_t)((br << 1) + p) * 8192 + grow + r) * 512 + c] = f2bf(acc[f][n][r] + bv);
      } else {
        const int b_ = grow >> 9, s0 = grow & 511;
        const int hi = c >> 7, dk = c & 127;
        us4 pk;
        #pragma unroll
        for (int r = 0; r < 4; ++r) pk[r] = f2bf(acc[f][n][r] + bv);
        *(us4*)(vtp + (((size_t)(br * 16 + b_) * 4 + hi) * 128 + dk) * 512 + s0) = pk;
      }
    }
  }
}

// ---------------------------------------------------------------- attention --
// Barrier-free; K/V fragments direct from global (L2-resident). ALL loops that
// index sc[] are fully unrolled (rule #20: partial unroll -> scratch).
__global__ __launch_bounds__(256, 2)
void attn_kernel(const unsigned short* __restrict__ qk, const unsigned short* __restrict__ vt,
                 const unsigned* __restrict__ mp, unsigned short* __restrict__ outp)
{
  __shared__ unsigned short Pl[4][16 * 40];
  __shared__ unsigned Mk[4][16 * 17];
  const int tid = threadIdx.x;
  const int w = tid >> 6, lane = tid & 63;
  const int lr = lane & 15, lh = lane >> 4;
  const int id = blockIdx.x;
  const int pair = (id & 7) * 24 + (id >> 6);
  const int qt = (id >> 3) & 7;
  const int br = pair >> 6, bh = pair & 63;
  const int b = bh >> 2, h = bh & 3;
  const int q0 = (qt << 6) + (w << 4);

  const unsigned short* qbase = qk + ((size_t)(br * 2 + 0) * 8192 + (size_t)b * 512) * 512 + h * 128;
  const unsigned short* kbase = qk + ((size_t)(br * 2 + 1) * 8192 + (size_t)b * 512) * 512 + h * 128;
  const unsigned short* vbase = vt + ((size_t)(br * 16 + b) * 4 + h) * 128 * 512;
  const unsigned* mrow = mp + ((size_t)br * 8192 + (size_t)b * 512 + (qt << 6) + (w << 4)) * 16;

  unsigned* mk = Mk[w];
  #pragma unroll
  for (int u = 0; u < 4; ++u){
    const int idx = (lane << 2) + u;
    const int rw = idx >> 4, wd = idx & 15;
    mk[rw * 17 + wd] = mrow[rw * 16 + wd];
  }
  asm volatile("s_waitcnt lgkmcnt(0)" ::: "memory");

  bfx8 aq[4];
  #pragma unroll
  for (int t = 0; t < 4; ++t)
    aq[t] = *(const bfx8*)(qbase + (size_t)(q0 + lr) * 512 + (t << 5) + (lh << 3));

  f32x4 sc[16][2];
  const float scale = 0.08838834764831845f;  // 1/sqrt(128)

  // phase 1: scores = QK^T directly from global K (FULL unroll)
  #pragma unroll
  for (int kt = 0; kt < 16; ++kt){
    #pragma unroll
    for (int j = 0; j < 2; ++j){
      const int rk = (kt << 5) + (j << 4) + lr;
      f32x4 a2 = (f32x4)0.f;
      #pragma unroll
      for (int t = 0; t < 4; ++t){
        bfx8 bk = *(const bfx8*)(kbase + (size_t)rk * 512 + (t << 5) + (lh << 3));
        a2 = mfma16(aq[t], bk, a2);
      }
      #pragma unroll
      for (int r = 0; r < 4; ++r){
        const unsigned mword = mk[((lh << 2) + r) * 17 + kt];
        const int bit = (mword >> ((j << 4) + lr)) & 1;
        sc[kt][j][r] = bit ? -1e9f : a2[r] * scale;
      }
    }
  }

  // phase 2: wave-parallel softmax (FULL unroll everywhere)
  float mx[4] = {-3e38f, -3e38f, -3e38f, -3e38f};
  #pragma unroll
  for (int kt = 0; kt < 16; ++kt)
    #pragma unroll
    for (int j = 0; j < 2; ++j)
      #pragma unroll
      for (int r = 0; r < 4; ++r) mx[r] = fmaxf(mx[r], sc[kt][j][r]);
  #pragma unroll
  for (int s = 1; s < 16; s <<= 1)
    #pragma unroll
    for (int r = 0; r < 4; ++r) mx[r] = fmaxf(mx[r], __shfl_xor(mx[r], s, 64));
  float sm[4] = {0.f, 0.f, 0.f, 0.f};
  #pragma unroll
  for (int kt = 0; kt < 16; ++kt)
    #pragma unroll
    for (int j = 0; j < 2; ++j)
      #pragma unroll
      for (int r = 0; r < 4; ++r){
        const float pv = __expf(sc[kt][j][r] - mx[r]);
        sc[kt][j][r] = pv;
        sm[r] += pv;
      }
  #pragma unroll
  for (int s = 1; s < 16; s <<= 1)
    #pragma unroll
    for (int r = 0; r < 4; ++r) sm[r] += __shfl_xor(sm[r], s, 64);
  float linv[4];
  #pragma unroll
  for (int r = 0; r < 4; ++r) linv[r] = 1.f / sm[r];

  // phase 3: O = P*V (FULL unroll; V direct from global)
  f32x4 ao[8];
  #pragma unroll
  for (int j = 0; j < 8; ++j) ao[j] = (f32x4)0.f;
  unsigned short* pw = Pl[w];
  #pragma unroll
  for (int kt = 0; kt < 16; ++kt){
    #pragma unroll
    for (int j = 0; j < 2; ++j)
      #pragma unroll
      for (int r = 0; r < 4; ++r)
        pw[((lh << 2) + r) * 40 + (j << 4) + lr] = f2bf(sc[kt][j][r] * linv[r]);
    asm volatile("s_waitcnt lgkmcnt(0)" ::: "memory");
    bfx8 pa = *(const bfx8*)(pw + lr * 40 + (lh << 3));
    #pragma unroll
    for (int j = 0; j < 8; ++j){
      bfx8 bv = *(const bfx8*)(vbase + (size_t)((j << 4) + lr) * 512 + (kt << 5) + (lh << 3));
      ao[j] = mfma16(pa, bv, ao[j]);
    }
    asm volatile("" ::: "memory");
  }
  const size_t obase = (size_t)(b * 512) * 1536 + br * 512 + h * 128;
  #pragma unroll
  for (int j = 0; j < 8; ++j){
    const int d = (j << 4) + lr;
    #pragma unroll
    for (int r = 0; r < 4; ++r){
      const int q = q0 + (lh << 2) + r;
      outp[obase + (size_t)q * 1536 + d] = f2bf(ao[j][r]);
    }
  }
}

// ---------------------------------------------------------------- out3 -------
__global__ __launch_bounds__(256, 4)
void out3_kernel(const unsigned short* __restrict__ t2, const float* __restrict__ w,
                 const float* __restrict__ b2, float* __restrict__ outp)
{
  const int row = (blockIdx.x << 2) + (threadIdx.x >> 6);
  const int lane = threadIdx.x & 63;
  const unsigned short* rp = t2 + (size_t)row * 256 + (lane << 2);
  float a0 = 0.f, a1 = 0.f;
  #pragma unroll
  for (int k = 0; k < 4; ++k){
    const float v = bf2f(rp[k]);
    const int kk = (lane << 2) + k;
    a0 += v * w[kk * 2 + 0];
    a1 += v * w[kk * 2 + 1];
  }
  #pragma unroll
  for (int s = 1; s < 64; s <<= 1){
    a0 += __shfl_xor(a0, s, 64);
    a1 += __shfl_xor(a1, s, 64);
  }
  if (lane == 0){
    outp[(size_t)row * 2 + 0] = a0 + b2[0];
    outp[(size_t)row * 2 + 1] = a1 + b2[1];
  }
}

// ---------------------------------------------------------------- launch -----
extern "C" void kernel_launch(void* const* d_in, const int* in_sizes, int n_in,
                              void* d_out, int out_size, void* d_ws, size_t ws_size,
                              hipStream_t stream)
{
  const float* x      = (const float*)d_in[0];
  const float* cond   = (const float*)d_in[1];
  const int*   mdoor  = (const int*)d_in[2];
  const int*   mself  = (const int*)d_in[3];
  const int*   mgen   = (const int*)d_in[4];
  const float* attn_w = (const float*)d_in[5];
  const float* attn_b = (const float*)d_in[6];
  const float* ff_w1  = (const float*)d_in[7];
  const float* ff_b1  = (const float*)d_in[8];
  const float* ff_w2  = (const float*)d_in[9];
  const float* ff_b2  = (const float*)d_in[10];
  const float* in_w   = (const float*)d_in[11];
  const float* in_b   = (const float*)d_in[12];
  const float* cond_w = (const float*)d_in[13];
  const float* cond_b = (const float*)d_in[14];
  const float* out1_w = (const float*)d_in[15];
  const float* out1_b = (const float*)d_in[16];
  const float* out2_w = (const float*)d_in[17];
  const float* out2_b = (const float*)d_in[18];
  const float* out3_w = (const float*)d_in[19];
  const float* out3_b = (const float*)d_in[20];

  char* p = (char*)d_ws;
  auto carve = [&](size_t bytes) -> char* {
    char* r = p; p += (bytes + 255) & ~(size_t)255; return r;
  };
  float*          h    = (float*)carve(8192ull * 512 * 4);
  unsigned short* h2   = (unsigned short*)carve(8192ull * 512 * 2);
  unsigned short* bqkv = (unsigned short*)carve(4ull * 4608 * 512 * 2);
  unsigned short* bout = (unsigned short*)carve(4ull * 512 * 1536 * 2);
  unsigned short* bff1 = (unsigned short*)carve(4ull * 1024 * 512 * 2);
  unsigned short* bff2 = (unsigned short*)carve(4ull * 512 * 1024 * 2);
  unsigned short* bo1  = (unsigned short*)carve(512ull * 512 * 2);
  unsigned short* bo2  = (unsigned short*)carve(256ull * 512 * 2);
  unsigned short* qkb  = (unsigned short*)carve(6ull * 8192 * 512 * 2);
  unsigned short* vtb  = (unsigned short*)carve(3ull * 16 * 4 * 128 * 512 * 2);
  unsigned short* att  = (unsigned short*)carve(8192ull * 1536 * 2);
  unsigned short* t    = (unsigned short*)carve(8192ull * 1024 * 2);
  unsigned short* t2   = (unsigned short*)carve(8192ull * 256 * 2);
  unsigned long long* mpk = (unsigned long long*)carve(24576ull * 8 * 8);
  float* outf = (float*)d_out;

  wconv_kernel<<<dim3(16, 16, 58), 256, 0, stream>>>(attn_w, ff_w1, ff_w2, out1_w, out2_w,
                                                     bqkv, bout, bff1, bff2, bo1, bo2);
  mpack_kernel<<<dim3(6144), 256, 0, stream>>>(mdoor, mself, mgen, mpk);
  embed_kernel<<<dim3(1024), 256, 0, stream>>>(x, cond, in_w, in_b, cond_w, cond_b, h);
  for (int l = 0; l < 4; ++l){
    inorm_kernel<<<dim3(2048), 256, 0, stream>>>(h, h2);
    gemm256_qkv<<<dim3(576), 512, 0, stream>>>(h2, bqkv + (size_t)l * 4608 * 512,
        attn_b + (size_t)l * 6144, qkb, vtb, 512);
    attn_kernel<<<dim3(1536), 256, 0, stream>>>(qkb, vtb, (const unsigned*)mpk, att);
    gemm_bt<2><<<dim3(64, 4), 256, 0, stream>>>(att, bout + (size_t)l * 512 * 1536,
        nullptr, h, nullptr, 8192, 512, 1536);
    inorm_kernel<<<dim3(2048), 256, 0, stream>>>(h, h2);
    gemm_bt<1><<<dim3(64, 8), 256, 0, stream>>>(h2, bff1 + (size_t)l * 1024 * 512,
        ff_b1 + (size_t)l * 1024, nullptr, t, 8192, 1024, 512);
    gemm_bt<2><<<dim3(64, 4), 256, 0, stream>>>(t, bff2 + (size_t)l * 512 * 1024,
        ff_b2 + (size_t)l * 512, h, nullptr, 8192, 512, 1024);
  }
  f2b_kernel<<<dim3(4096), 256, 0, stream>>>(h, h2, 8192 * 512);
  gemm_bt<1><<<dim3(64, 4), 256, 0, stream>>>(h2, bo1, out1_b, nullptr, att, 8192, 512, 512);
  gemm_bt<1><<<dim3(64, 2), 256, 0, stream>>>(att, bo2, out2_b, nullptr, t2, 8192, 256, 512);
  out3_kernel<<<dim3(2048), 256, 0, stream>>>(t2, out3_w, out3_b, outf);
}

// Round 5
// 1221.058 us; speedup vs baseline: 2.1281x; 1.4217x over previous
//
#include <hip/hip_runtime.h>
#include <hip/hip_bf16.h>

#define DEV static __device__ __forceinline__

typedef __attribute__((ext_vector_type(8))) short bfx8;
typedef __attribute__((ext_vector_type(4))) float f32x4;
typedef __attribute__((ext_vector_type(4))) unsigned short us4;

DEV unsigned short f2bf(float f){
  unsigned u = __builtin_bit_cast(unsigned, f);
  u += 0x7fffu + ((u >> 16) & 1u);
  return (unsigned short)(u >> 16);
}
DEV float bf2f(unsigned short h){
  unsigned u = ((unsigned)h) << 16;
  return __builtin_bit_cast(float, u);
}
DEV void gld16(const void* g, void* l){
  __builtin_amdgcn_global_load_lds((const __attribute__((address_space(1))) void*)g,
                                   (__attribute__((address_space(3))) void*)l, 16, 0, 0);
}
DEV f32x4 mfma16(bfx8 a, bfx8 b, f32x4 c){
  return __builtin_amdgcn_mfma_f32_16x16x32_bf16(a, b, c, 0, 0, 0);
}

#define BAR() do{ asm volatile("" ::: "memory"); __builtin_amdgcn_s_barrier(); \
                  asm volatile("" ::: "memory"); }while(0)

// ---------------------------------------------------------------- weights ----
__global__ __launch_bounds__(256, 2)
void wconv_kernel(const float* __restrict__ attn_w, const float* __restrict__ ff_w1,
                  const float* __restrict__ ff_w2, const float* __restrict__ out1_w,
                  const float* __restrict__ out2_w,
                  unsigned short* __restrict__ bqkv, unsigned short* __restrict__ bout,
                  unsigned short* __restrict__ bff1, unsigned short* __restrict__ bff2,
                  unsigned short* __restrict__ bo1, unsigned short* __restrict__ bo2)
{
  __shared__ float ts[64][65];
  const int z = blockIdx.z;
  const float* src; unsigned short* dst; int K, N, stride;
  if (z < 48){
    int l = z / 12, br = (z % 12) >> 2, p = z & 3;
    src = attn_w + (size_t)z * 262144; K = 512; N = 512;
    if (p < 3){ dst = bqkv + (size_t)l * 4608 * 512 + (size_t)(br * 3 + p) * 262144; stride = 512; }
    else      { dst = bout + (size_t)l * 512 * 1536 + (size_t)br * 512;              stride = 1536; }
  } else if (z < 52){
    int l = z - 48; src = ff_w1 + (size_t)l * 524288; K = 512; N = 1024;
    dst = bff1 + (size_t)l * 524288; stride = 512;
  } else if (z < 56){
    int l = z - 52; src = ff_w2 + (size_t)l * 524288; K = 1024; N = 512;
    dst = bff2 + (size_t)l * 524288; stride = 1024;
  } else if (z == 56){
    src = out1_w; K = 512; N = 512; dst = bo1; stride = 512;
  } else {
    src = out2_w; K = 512; N = 256; dst = bo2; stride = 512;
  }
  const int n0 = blockIdx.x << 6, k0 = blockIdx.y << 6;
  if (n0 >= N || k0 >= K) return;
  const int tx = threadIdx.x & 63, ty = threadIdx.x >> 6;
  #pragma unroll
  for (int i = 0; i < 16; ++i){
    int row = (ty << 4) + i;
    ts[row][tx] = src[(size_t)(k0 + row) * N + n0 + tx];
  }
  __syncthreads();
  #pragma unroll
  for (int i = 0; i < 16; ++i){
    int row = (ty << 4) + i;
    dst[(size_t)(n0 + row) * stride + k0 + tx] = f2bf(ts[tx][row]);
  }
}

// ---------------------------------------------------------------- mask pack --
__global__ __launch_bounds__(256, 4)
void mpack_kernel(const int* __restrict__ m0, const int* __restrict__ m1,
                  const int* __restrict__ m2, unsigned long long* __restrict__ mp)
{
  const int row = (blockIdx.x << 2) + (threadIdx.x >> 6);
  const int lane = threadIdx.x & 63;
  const int* src = (row < 8192) ? (m0 + (size_t)row * 512)
                 : (row < 16384 ? (m1 + (size_t)(row - 8192) * 512)
                                : (m2 + (size_t)(row - 16384) * 512));
  #pragma unroll
  for (int c = 0; c < 8; ++c){
    const int v = src[(c << 6) + lane];
    const unsigned long long b = __ballot(v != 0);
    if (lane == c) mp[(size_t)row * 8 + c] = b;
  }
}

// ---------------------------------------------------------------- embed ------
__global__ __launch_bounds__(256, 4)
void embed_kernel(const float* __restrict__ x, const float* __restrict__ cond,
                  const float* __restrict__ in_w, const float* __restrict__ in_b,
                  const float* __restrict__ cond_w, const float* __restrict__ cond_b,
                  float* __restrict__ h)
{
  __shared__ float xs[8][18];
  __shared__ float cs[8][89];
  const int m0 = blockIdx.x << 3;
  const int tid = threadIdx.x;
  for (int i = tid; i < 144; i += 256) xs[i / 18][i % 18] = x[(size_t)m0 * 18 + i];
  for (int i = tid; i < 712; i += 256) cs[i / 89][i % 89] = cond[(size_t)m0 * 89 + i];
  __syncthreads();
  #pragma unroll
  for (int hf = 0; hf < 2; ++hf){
    const int c = tid + (hf << 8);
    const float bsum = in_b[c] + cond_b[c];
    float a[8];
    #pragma unroll
    for (int mi = 0; mi < 8; ++mi) a[mi] = bsum;
    #pragma unroll
    for (int k = 0; k < 18; ++k){
      const float wv = in_w[k * 512 + c];
      #pragma unroll
      for (int mi = 0; mi < 8; ++mi) a[mi] += xs[mi][k] * wv;
    }
    for (int k = 0; k < 89; ++k){
      const float wv = cond_w[k * 512 + c];
      #pragma unroll
      for (int mi = 0; mi < 8; ++mi) a[mi] += cs[mi][k] * wv;
    }
    #pragma unroll
    for (int mi = 0; mi < 8; ++mi) h[(size_t)(m0 + mi) * 512 + c] = a[mi];
  }
}

// ---------------------------------------------------------------- inorm ------
__global__ __launch_bounds__(256, 4)
void inorm_kernel(const float* __restrict__ in, unsigned short* __restrict__ ob)
{
  const int wid = (blockIdx.x << 2) + (threadIdx.x >> 6);
  const int lane = threadIdx.x & 63;
  const float* row = in + (size_t)wid * 512;
  const float4 v0 = *(const float4*)(row + (lane << 2));
  const float4 v1 = *(const float4*)(row + 256 + (lane << 2));
  float s = v0.x + v0.y + v0.z + v0.w + v1.x + v1.y + v1.z + v1.w;
  float q = v0.x*v0.x + v0.y*v0.y + v0.z*v0.z + v0.w*v0.w
          + v1.x*v1.x + v1.y*v1.y + v1.z*v1.z + v1.w*v1.w;
  #pragma unroll
  for (int sh = 1; sh < 64; sh <<= 1){
    s += __shfl_xor(s, sh, 64);
    q += __shfl_xor(q, sh, 64);
  }
  const float mean = s * (1.f / 512.f);
  const float var = q * (1.f / 512.f) - mean * mean;
  const float rs = rsqrtf(var + 1e-5f);
  us4 o0, o1;
  o0[0] = f2bf((v0.x - mean) * rs); o0[1] = f2bf((v0.y - mean) * rs);
  o0[2] = f2bf((v0.z - mean) * rs); o0[3] = f2bf((v0.w - mean) * rs);
  o1[0] = f2bf((v1.x - mean) * rs); o1[1] = f2bf((v1.y - mean) * rs);
  o1[2] = f2bf((v1.z - mean) * rs); o1[3] = f2bf((v1.w - mean) * rs);
  *(us4*)(ob + (size_t)wid * 512 + (lane << 2)) = o0;
  *(us4*)(ob + (size_t)wid * 512 + 256 + (lane << 2)) = o1;
}

__global__ void f2b_kernel(const float* __restrict__ in, unsigned short* __restrict__ ob, int n)
{
  const int i = (blockIdx.x * 256 + threadIdx.x) << 2;
  if (i >= n) return;
  const float4 v = *(const float4*)(in + i);
  us4 o; o[0] = f2bf(v.x); o[1] = f2bf(v.y); o[2] = f2bf(v.z); o[3] = f2bf(v.w);
  *(us4*)(ob + i) = o;
}

// ---------------------------------------------------------------- GEMM 128 ---
// m97-style 128x128 kernel.
// MODE 1: Cb=bf16(relu(acc+bias)); MODE 2: Cf+=acc+bias; MODE 3: QKV scatter.
template<int MODE>
__global__ __launch_bounds__(256, 2)
void gemm_bt(const unsigned short* __restrict__ A, const unsigned short* __restrict__ B,
             const float* __restrict__ bias, float* __restrict__ Cf,
             unsigned short* __restrict__ Cb, unsigned short* __restrict__ qkp,
             unsigned short* __restrict__ vtp, int M, int N, int K)
{
  __shared__ unsigned short As[128 * 64];
  __shared__ unsigned short Bs[128 * 64];
  const int tid = threadIdx.x;
  const int w = tid >> 6, lane = tid & 63;
  const int wm = w >> 1, wn = w & 1;
  const int lr = lane & 15, lh = lane >> 4;
  const int m0 = blockIdx.x << 7, n0 = blockIdx.y << 7;
  const int rA = lane >> 3;
  const int cA = (lane & 7) << 3;

  f32x4 acc[4][4];
  #pragma unroll
  for (int i = 0; i < 4; ++i)
    #pragma unroll
    for (int j = 0; j < 4; ++j) acc[i][j] = (f32x4)0.f;

  const int nkt = K >> 6;
  auto stage = [&](int kt){
    #pragma unroll
    for (int c = 0; c < 4; ++c){
      const int r = (c << 5) + (w << 3) + rA;
      gld16(A + (size_t)(m0 + r) * K + (kt << 6) + cA,
            (char*)As + ((c << 5) + (w << 3)) * 128);
      gld16(B + (size_t)(n0 + r) * K + (kt << 6) + cA,
            (char*)Bs + ((c << 5) + (w << 3)) * 128);
    }
  };
  stage(0);
  for (int kt = 0; kt < nkt; ++kt){
    __syncthreads();
    #pragma unroll
    for (int kk = 0; kk < 2; ++kk){
      bfx8 af[4], bg[4];
      #pragma unroll
      for (int i = 0; i < 4; ++i)
        af[i] = *(const bfx8*)(As + ((wm << 6) + (i << 4) + lr) * 64 + (kk << 5) + (lh << 3));
      #pragma unroll
      for (int j = 0; j < 4; ++j)
        bg[j] = *(const bfx8*)(Bs + ((wn << 6) + (j << 4) + lr) * 64 + (kk << 5) + (lh << 3));
      #pragma unroll
      for (int i = 0; i < 4; ++i)
        #pragma unroll
        for (int j = 0; j < 4; ++j)
          acc[i][j] = mfma16(af[i], bg[j], acc[i][j]);
    }
    __syncthreads();
    if (kt + 1 < nkt) stage(kt + 1);
  }
  #pragma unroll
  for (int i = 0; i < 4; ++i){
    const int row = m0 + (wm << 6) + (i << 4) + (lh << 2);
    #pragma unroll
    for (int j = 0; j < 4; ++j){
      const int col = n0 + (wn << 6) + (j << 4) + lr;
      if constexpr (MODE == 1){
        const float bv = bias ? bias[col] : 0.f;
        #pragma unroll
        for (int r = 0; r < 4; ++r){
          float v = acc[i][j][r] + bv;
          v = fmaxf(v, 0.f);
          Cb[(size_t)(row + r) * N + col] = f2bf(v);
        }
      } else if constexpr (MODE == 2){
        const float bv = bias ? bias[col] : 0.f;
        #pragma unroll
        for (int r = 0; r < 4; ++r)
          Cf[(size_t)(row + r) * N + col] += acc[i][j][r] + bv;
      } else {
        const int br = col / 1536;
        const int rem = col - br * 1536;
        const int p = rem >> 9;
        const int c = rem & 511;
        const float bv = bias ? bias[(size_t)((br << 2) + p) * 512 + c] : 0.f;
        if (p < 2){
          #pragma unroll
          for (int r = 0; r < 4; ++r)
            qkp[((size_t)((br << 1) + p) * 8192 + row + r) * 512 + c] = f2bf(acc[i][j][r] + bv);
        } else {
          const int b_ = row >> 9, s0 = row & 511;
          const int hi = c >> 7, dk = c & 127;
          us4 pk;
          #pragma unroll
          for (int r = 0; r < 4; ++r) pk[r] = f2bf(acc[i][j][r] + bv);
          *(us4*)(vtp + (((size_t)(br * 16 + b_) * 4 + hi) * 128 + dk) * 512 + s0) = pk;
        }
      }
    }
  }
}

// ---------------------------------------------------------------- attention --
// Flash-style: 8 waves x 16 q-rows = 128 rows/block; K+V tiles (32 k-cols)
// triple-buffered in LDS, counted vmcnt(2) + raw barriers; online softmax
// with THR=8 deferred rescale; both-sides XOR swizzles on K and V tiles.
__global__ __launch_bounds__(512, 4)
void attn_kernel(const unsigned short* __restrict__ qk, const unsigned short* __restrict__ vt,
                 const unsigned* __restrict__ mp, unsigned short* __restrict__ outp)
{
  __shared__ unsigned short KV[3][8192];   // per buf: K [32][128] | V [128][32]
  __shared__ unsigned short Pl[8][16 * 40];
  __shared__ unsigned Mk[8][16 * 17];
  const int tid = threadIdx.x;
  const int w = tid >> 6, lane = tid & 63;
  const int lr = lane & 15, lh = lane >> 4;
  const int id = blockIdx.x;
  const int wg = (id & 7) * 96 + (id >> 3);          // XCD swizzle (768 = 8*96)
  const int qt = wg & 3, head = wg >> 2;             // 4 q-tiles of 128 rows
  const int br = head >> 6, bh = head & 63;
  const int b = bh >> 2, h = bh & 3;
  const int q0 = (qt << 7) + (w << 4);

  const unsigned short* qbase = qk + ((size_t)(br * 2 + 0) * 8192 + (size_t)b * 512) * 512 + h * 128;
  const unsigned short* kbase = qk + ((size_t)(br * 2 + 1) * 8192 + (size_t)b * 512) * 512 + h * 128;
  const unsigned short* vbase = vt + ((size_t)(br * 16 + b) * 4 + h) * 128 * 512;
  const unsigned* mrow = mp + ((size_t)br * 8192 + (size_t)b * 512 + q0) * 16;

  // per-wave packed-mask fill (wave-local; lgkm-fenced)
  unsigned* mk = Mk[w];
  #pragma unroll
  for (int u = 0; u < 4; ++u){
    const int idx = (lane << 2) + u;
    const int rw = idx >> 4, wd = idx & 15;
    mk[rw * 17 + wd] = mrow[rw * 16 + wd];
  }
  asm volatile("s_waitcnt lgkmcnt(0)" ::: "memory");
  __builtin_amdgcn_sched_barrier(0);

  bfx8 aq[4];
  #pragma unroll
  for (int t = 0; t < 4; ++t)
    aq[t] = *(const bfx8*)(qbase + (size_t)(q0 + lr) * 512 + (t << 5) + (lh << 3));

  // staging geometry (per wave: 1KB of K + 1KB of V per tile)
  const int krow = (w << 2) + (lane >> 4);                 // local K row 0..31
  const int kg = (lane & 15) ^ (krow & 7);
  const int vrow = (w << 4) + (lane >> 2);                 // local V(dk) row 0..127
  const int vg = (lane & 3) ^ ((vrow & 3) ^ ((vrow >> 2) & 3));
  auto stageKt = [&](int kt, int buf){
    gld16(kbase + ((size_t)((kt << 5) + krow) << 9) + (kg << 3),
          (char*)&KV[buf][w << 9]);
    gld16(vbase + ((size_t)vrow << 9) + (kt << 5) + (vg << 3),
          (char*)&KV[buf][4096 + (w << 9)]);
  };

  const float scale = 0.08838834764831845f;  // 1/sqrt(128)
  f32x4 ao[8];
  #pragma unroll
  for (int j = 0; j < 8; ++j) ao[j] = (f32x4)0.f;
  float m[4]  = {-3e38f, -3e38f, -3e38f, -3e38f};
  float lp[4] = {0.f, 0.f, 0.f, 0.f};
  unsigned short* pw = Pl[w];

  stageKt(0, 0); stageKt(1, 1);
  int bcur = 0;
  for (int kt = 0; kt < 16; ++kt){
    if (kt < 15) asm volatile("s_waitcnt vmcnt(2)" ::: "memory");
    else         asm volatile("s_waitcnt vmcnt(0)" ::: "memory");
    BAR();
    if (kt < 14){
      const int bst = (bcur == 0) ? 2 : bcur - 1;   // (kt+2)%3
      stageKt(kt + 2, bst);
    }
    const unsigned short* Kb = &KV[bcur][0];
    const unsigned short* Vb = &KV[bcur][4096];

    // QK^T for this 32-col tile
    f32x4 st[2];
    #pragma unroll
    for (int j = 0; j < 2; ++j){
      const int rk = (j << 4) + lr;
      f32x4 a2 = (f32x4)0.f;
      __builtin_amdgcn_s_setprio(1);
      #pragma unroll
      for (int t = 0; t < 4; ++t){
        const int s = ((t << 2) + lh) ^ (rk & 7);
        bfx8 bk = *(const bfx8*)&Kb[rk * 128 + (s << 3)];
        a2 = mfma16(aq[t], bk, a2);
      }
      __builtin_amdgcn_s_setprio(0);
      #pragma unroll
      for (int r = 0; r < 4; ++r){
        const unsigned mword = mk[((lh << 2) + r) * 17 + kt];
        const int bit = (mword >> ((j << 4) + lr)) & 1;
        st[j][r] = bit ? -1e9f : a2[r] * scale;
      }
    }

    // online softmax update (deferred rescale, THR=8)
    float tm[4];
    #pragma unroll
    for (int r = 0; r < 4; ++r) tm[r] = fmaxf(st[0][r], st[1][r]);
    #pragma unroll
    for (int s = 1; s < 16; s <<= 1)
      #pragma unroll
      for (int r = 0; r < 4; ++r) tm[r] = fmaxf(tm[r], __shfl_xor(tm[r], s, 64));
    bool need = false;
    #pragma unroll
    for (int r = 0; r < 4; ++r) need |= (tm[r] > m[r] + 8.f);
    if (__any(need)){
      #pragma unroll
      for (int r = 0; r < 4; ++r){
        const float mn = fmaxf(m[r], tm[r]);
        const float f = __expf(m[r] - mn);
        m[r] = mn; lp[r] *= f;
        #pragma unroll
        for (int j = 0; j < 8; ++j) ao[j][r] *= f;
      }
    }
    #pragma unroll
    for (int j = 0; j < 2; ++j)
      #pragma unroll
      for (int r = 0; r < 4; ++r){
        const float p = __expf(st[j][r] - m[r]);
        lp[r] += p;
        pw[((lh << 2) + r) * 40 + (j << 4) + lr] = f2bf(p);
      }
    asm volatile("s_waitcnt lgkmcnt(0)" ::: "memory");
    __builtin_amdgcn_sched_barrier(0);
    bfx8 pa = *(const bfx8*)(pw + lr * 40 + (lh << 3));

    // PV for this tile
    __builtin_amdgcn_s_setprio(1);
    #pragma unroll
    for (int j = 0; j < 8; ++j){
      const int dd = (j << 4) + lr;
      const int s = lh ^ ((dd & 3) ^ ((dd >> 2) & 3));
      bfx8 bv = *(const bfx8*)&Vb[dd * 32 + (s << 3)];
      ao[j] = mfma16(pa, bv, ao[j]);
    }
    __builtin_amdgcn_s_setprio(0);
    asm volatile("" ::: "memory");
    bcur = (bcur == 2) ? 0 : bcur + 1;
  }

  // epilogue: finish l, normalize, store
  #pragma unroll
  for (int s = 1; s < 16; s <<= 1)
    #pragma unroll
    for (int r = 0; r < 4; ++r) lp[r] += __shfl_xor(lp[r], s, 64);
  float linv[4];
  #pragma unroll
  for (int r = 0; r < 4; ++r) linv[r] = 1.f / lp[r];
  const size_t obase = (size_t)(b * 512) * 1536 + br * 512 + h * 128;
  #pragma unroll
  for (int j = 0; j < 8; ++j){
    const int d = (j << 4) + lr;
    #pragma unroll
    for (int r = 0; r < 4; ++r){
      const int q = q0 + (lh << 2) + r;
      outp[obase + (size_t)q * 1536 + d] = f2bf(ao[j][r] * linv[r]);
    }
  }
}

// ---------------------------------------------------------------- out3 -------
__global__ __launch_bounds__(256, 4)
void out3_kernel(const unsigned short* __restrict__ t2, const float* __restrict__ w,
                 const float* __restrict__ b2, float* __restrict__ outp)
{
  const int row = (blockIdx.x << 2) + (threadIdx.x >> 6);
  const int lane = threadIdx.x & 63;
  const unsigned short* rp = t2 + (size_t)row * 256 + (lane << 2);
  float a0 = 0.f, a1 = 0.f;
  #pragma unroll
  for (int k = 0; k < 4; ++k){
    const float v = bf2f(rp[k]);
    const int kk = (lane << 2) + k;
    a0 += v * w[kk * 2 + 0];
    a1 += v * w[kk * 2 + 1];
  }
  #pragma unroll
  for (int s = 1; s < 64; s <<= 1){
    a0 += __shfl_xor(a0, s, 64);
    a1 += __shfl_xor(a1, s, 64);
  }
  if (lane == 0){
    outp[(size_t)row * 2 + 0] = a0 + b2[0];
    outp[(size_t)row * 2 + 1] = a1 + b2[1];
  }
}

// ---------------------------------------------------------------- launch -----
extern "C" void kernel_launch(void* const* d_in, const int* in_sizes, int n_in,
                              void* d_out, int out_size, void* d_ws, size_t ws_size,
                              hipStream_t stream)
{
  const float* x      = (const float*)d_in[0];
  const float* cond   = (const float*)d_in[1];
  const int*   mdoor  = (const int*)d_in[2];
  const int*   mself  = (const int*)d_in[3];
  const int*   mgen   = (const int*)d_in[4];
  const float* attn_w = (const float*)d_in[5];
  const float* attn_b = (const float*)d_in[6];
  const float* ff_w1  = (const float*)d_in[7];
  const float* ff_b1  = (const float*)d_in[8];
  const float* ff_w2  = (const float*)d_in[9];
  const float* ff_b2  = (const float*)d_in[10];
  const float* in_w   = (const float*)d_in[11];
  const float* in_b   = (const float*)d_in[12];
  const float* cond_w = (const float*)d_in[13];
  const float* cond_b = (const float*)d_in[14];
  const float* out1_w = (const float*)d_in[15];
  const float* out1_b = (const float*)d_in[16];
  const float* out2_w = (const float*)d_in[17];
  const float* out2_b = (const float*)d_in[18];
  const float* out3_w = (const float*)d_in[19];
  const float* out3_b = (const float*)d_in[20];

  char* p = (char*)d_ws;
  auto carve = [&](size_t bytes) -> char* {
    char* r = p; p += (bytes + 255) & ~(size_t)255; return r;
  };
  float*          h    = (float*)carve(8192ull * 512 * 4);
  unsigned short* h2   = (unsigned short*)carve(8192ull * 512 * 2);
  unsigned short* bqkv = (unsigned short*)carve(4ull * 4608 * 512 * 2);
  unsigned short* bout = (unsigned short*)carve(4ull * 512 * 1536 * 2);
  unsigned short* bff1 = (unsigned short*)carve(4ull * 1024 * 512 * 2);
  unsigned short* bff2 = (unsigned short*)carve(4ull * 512 * 1024 * 2);
  unsigned short* bo1  = (unsigned short*)carve(512ull * 512 * 2);
  unsigned short* bo2  = (unsigned short*)carve(256ull * 512 * 2);
  unsigned short* qkb  = (unsigned short*)carve(6ull * 8192 * 512 * 2);
  unsigned short* vtb  = (unsigned short*)carve(3ull * 16 * 4 * 128 * 512 * 2);
  unsigned short* att  = (unsigned short*)carve(8192ull * 1536 * 2);
  unsigned short* t    = (unsigned short*)carve(8192ull * 1024 * 2);
  unsigned short* t2   = (unsigned short*)carve(8192ull * 256 * 2);
  unsigned long long* mpk = (unsigned long long*)carve(24576ull * 8 * 8);
  float* outf = (float*)d_out;

  wconv_kernel<<<dim3(16, 16, 58), 256, 0, stream>>>(attn_w, ff_w1, ff_w2, out1_w, out2_w,
                                                     bqkv, bout, bff1, bff2, bo1, bo2);
  mpack_kernel<<<dim3(6144), 256, 0, stream>>>(mdoor, mself, mgen, mpk);
  embed_kernel<<<dim3(1024), 256, 0, stream>>>(x, cond, in_w, in_b, cond_w, cond_b, h);
  for (int l = 0; l < 4; ++l){
    inorm_kernel<<<dim3(2048), 256, 0, stream>>>(h, h2);
    gemm_bt<3><<<dim3(64, 36), 256, 0, stream>>>(h2, bqkv + (size_t)l * 4608 * 512,
        attn_b + (size_t)l * 6144, nullptr, nullptr, qkb, vtb, 8192, 4608, 512);
    attn_kernel<<<dim3(768), 512, 0, stream>>>(qkb, vtb, (const unsigned*)mpk, att);
    gemm_bt<2><<<dim3(64, 4), 256, 0, stream>>>(att, bout + (size_t)l * 512 * 1536,
        nullptr, h, nullptr, nullptr, nullptr, 8192, 512, 1536);
    inorm_kernel<<<dim3(2048), 256, 0, stream>>>(h, h2);
    gemm_bt<1><<<dim3(64, 8), 256, 0, stream>>>(h2, bff1 + (size_t)l * 1024 * 512,
        ff_b1 + (size_t)l * 1024, nullptr, t, nullptr, nullptr, 8192, 1024, 512);
    gemm_bt<2><<<dim3(64, 4), 256, 0, stream>>>(t, bff2 + (size_t)l * 512 * 1024,
        ff_b2 + (size_t)l * 512, h, nullptr, nullptr, nullptr, 8192, 512, 1024);
  }
  f2b_kernel<<<dim3(4096), 256, 0, stream>>>(h, h2, 8192 * 512);
  gemm_bt<1><<<dim3(64, 4), 256, 0, stream>>>(h2, bo1, out1_b, nullptr, att, nullptr, nullptr, 8192, 512, 512);
  gemm_bt<1><<<dim3(64, 2), 256, 0, stream>>>(att, bo2, out2_b, nullptr, t2, nullptr, nullptr, 8192, 256, 512);
  out3_kernel<<<dim3(2048), 256, 0, stream>>>(t2, out3_w, out3_b, outf);
}

// Round 6
// 1174.690 us; speedup vs baseline: 2.2121x; 1.0395x over previous
//
#include <hip/hip_runtime.h>
#include <hip/hip_bf16.h>

#define DEV static __device__ __forceinline__

typedef __attribute__((ext_vector_type(8))) short bfx8;
typedef __attribute__((ext_vector_type(4))) float f32x4;
typedef __attribute__((ext_vector_type(4))) unsigned short us4;

DEV unsigned short f2bf(float f){
  unsigned u = __builtin_bit_cast(unsigned, f);
  u += 0x7fffu + ((u >> 16) & 1u);
  return (unsigned short)(u >> 16);
}
DEV float bf2f(unsigned short h){
  unsigned u = ((unsigned)h) << 16;
  return __builtin_bit_cast(float, u);
}
DEV unsigned cvt_pk_bf16(float lo, float hi){
  unsigned r;
  asm("v_cvt_pk_bf16_f32 %0, %1, %2" : "=v"(r) : "v"(lo), "v"(hi));
  return r;
}
DEV void gld16(const void* g, void* l){
  __builtin_amdgcn_global_load_lds((const __attribute__((address_space(1))) void*)g,
                                   (__attribute__((address_space(3))) void*)l, 16, 0, 0);
}
DEV f32x4 mfma16(bfx8 a, bfx8 b, f32x4 c){
  return __builtin_amdgcn_mfma_f32_16x16x32_bf16(a, b, c, 0, 0, 0);
}

#define BAR() do{ asm volatile("" ::: "memory"); __builtin_amdgcn_s_barrier(); \
                  asm volatile("" ::: "memory"); }while(0)

// ---------------------------------------------------------------- weights ----
__global__ __launch_bounds__(256, 2)
void wconv_kernel(const float* __restrict__ attn_w, const float* __restrict__ ff_w1,
                  const float* __restrict__ ff_w2, const float* __restrict__ out1_w,
                  const float* __restrict__ out2_w,
                  unsigned short* __restrict__ bqkv, unsigned short* __restrict__ bout,
                  unsigned short* __restrict__ bff1, unsigned short* __restrict__ bff2,
                  unsigned short* __restrict__ bo1, unsigned short* __restrict__ bo2)
{
  __shared__ float ts[64][65];
  const int z = blockIdx.z;
  const float* src; unsigned short* dst; int K, N, stride;
  if (z < 48){
    int l = z / 12, br = (z % 12) >> 2, p = z & 3;
    src = attn_w + (size_t)z * 262144; K = 512; N = 512;
    if (p < 3){ dst = bqkv + (size_t)l * 4608 * 512 + (size_t)(br * 3 + p) * 262144; stride = 512; }
    else      { dst = bout + (size_t)l * 512 * 1536 + (size_t)br * 512;              stride = 1536; }
  } else if (z < 52){
    int l = z - 48; src = ff_w1 + (size_t)l * 524288; K = 512; N = 1024;
    dst = bff1 + (size_t)l * 524288; stride = 512;
  } else if (z < 56){
    int l = z - 52; src = ff_w2 + (size_t)l * 524288; K = 1024; N = 512;
    dst = bff2 + (size_t)l * 524288; stride = 1024;
  } else if (z == 56){
    src = out1_w; K = 512; N = 512; dst = bo1; stride = 512;
  } else {
    src = out2_w; K = 512; N = 256; dst = bo2; stride = 512;
  }
  const int n0 = blockIdx.x << 6, k0 = blockIdx.y << 6;
  if (n0 >= N || k0 >= K) return;
  const int tx = threadIdx.x & 63, ty = threadIdx.x >> 6;
  #pragma unroll
  for (int i = 0; i < 16; ++i){
    int row = (ty << 4) + i;
    ts[row][tx] = src[(size_t)(k0 + row) * N + n0 + tx];
  }
  __syncthreads();
  #pragma unroll
  for (int i = 0; i < 16; ++i){
    int row = (ty << 4) + i;
    dst[(size_t)(n0 + row) * stride + k0 + tx] = f2bf(ts[tx][row]);
  }
}

// ---------------------------------------------------------------- mask pack --
__global__ __launch_bounds__(256, 4)
void mpack_kernel(const int* __restrict__ m0, const int* __restrict__ m1,
                  const int* __restrict__ m2, unsigned long long* __restrict__ mp)
{
  const int row = (blockIdx.x << 2) + (threadIdx.x >> 6);
  const int lane = threadIdx.x & 63;
  const int* src = (row < 8192) ? (m0 + (size_t)row * 512)
                 : (row < 16384 ? (m1 + (size_t)(row - 8192) * 512)
                                : (m2 + (size_t)(row - 16384) * 512));
  #pragma unroll
  for (int c = 0; c < 8; ++c){
    const int v = src[(c << 6) + lane];
    const unsigned long long b = __ballot(v != 0);
    if (lane == c) mp[(size_t)row * 8 + c] = b;
  }
}

// ---------------------------------------------------------------- embed ------
__global__ __launch_bounds__(256, 4)
void embed_kernel(const float* __restrict__ x, const float* __restrict__ cond,
                  const float* __restrict__ in_w, const float* __restrict__ in_b,
                  const float* __restrict__ cond_w, const float* __restrict__ cond_b,
                  float* __restrict__ h)
{
  __shared__ float xs[8][18];
  __shared__ float cs[8][89];
  const int m0 = blockIdx.x << 3;
  const int tid = threadIdx.x;
  for (int i = tid; i < 144; i += 256) xs[i / 18][i % 18] = x[(size_t)m0 * 18 + i];
  for (int i = tid; i < 712; i += 256) cs[i / 89][i % 89] = cond[(size_t)m0 * 89 + i];
  __syncthreads();
  #pragma unroll
  for (int hf = 0; hf < 2; ++hf){
    const int c = tid + (hf << 8);
    const float bsum = in_b[c] + cond_b[c];
    float a[8];
    #pragma unroll
    for (int mi = 0; mi < 8; ++mi) a[mi] = bsum;
    #pragma unroll
    for (int k = 0; k < 18; ++k){
      const float wv = in_w[k * 512 + c];
      #pragma unroll
      for (int mi = 0; mi < 8; ++mi) a[mi] += xs[mi][k] * wv;
    }
    for (int k = 0; k < 89; ++k){
      const float wv = cond_w[k * 512 + c];
      #pragma unroll
      for (int mi = 0; mi < 8; ++mi) a[mi] += cs[mi][k] * wv;
    }
    #pragma unroll
    for (int mi = 0; mi < 8; ++mi) h[(size_t)(m0 + mi) * 512 + c] = a[mi];
  }
}

// ---------------------------------------------------------------- inorm ------
__global__ __launch_bounds__(256, 4)
void inorm_kernel(const float* __restrict__ in, unsigned short* __restrict__ ob)
{
  const int wid = (blockIdx.x << 2) + (threadIdx.x >> 6);
  const int lane = threadIdx.x & 63;
  const float* row = in + (size_t)wid * 512;
  const float4 v0 = *(const float4*)(row + (lane << 2));
  const float4 v1 = *(const float4*)(row + 256 + (lane << 2));
  float s = v0.x + v0.y + v0.z + v0.w + v1.x + v1.y + v1.z + v1.w;
  float q = v0.x*v0.x + v0.y*v0.y + v0.z*v0.z + v0.w*v0.w
          + v1.x*v1.x + v1.y*v1.y + v1.z*v1.z + v1.w*v1.w;
  #pragma unroll
  for (int sh = 1; sh < 64; sh <<= 1){
    s += __shfl_xor(s, sh, 64);
    q += __shfl_xor(q, sh, 64);
  }
  const float mean = s * (1.f / 512.f);
  const float var = q * (1.f / 512.f) - mean * mean;
  const float rs = rsqrtf(var + 1e-5f);
  us4 o0, o1;
  o0[0] = f2bf((v0.x - mean) * rs); o0[1] = f2bf((v0.y - mean) * rs);
  o0[2] = f2bf((v0.z - mean) * rs); o0[3] = f2bf((v0.w - mean) * rs);
  o1[0] = f2bf((v1.x - mean) * rs); o1[1] = f2bf((v1.y - mean) * rs);
  o1[2] = f2bf((v1.z - mean) * rs); o1[3] = f2bf((v1.w - mean) * rs);
  *(us4*)(ob + (size_t)wid * 512 + (lane << 2)) = o0;
  *(us4*)(ob + (size_t)wid * 512 + 256 + (lane << 2)) = o1;
}

__global__ void f2b_kernel(const float* __restrict__ in, unsigned short* __restrict__ ob, int n)
{
  const int i = (blockIdx.x * 256 + threadIdx.x) << 2;
  if (i >= n) return;
  const float4 v = *(const float4*)(in + i);
  us4 o; o[0] = f2bf(v.x); o[1] = f2bf(v.y); o[2] = f2bf(v.z); o[3] = f2bf(v.w);
  *(us4*)(ob + i) = o;
}

// ---------------------------------------------------------------- GEMM 128 ---
// m97-style 128x128 kernel.
// MODE 1: Cb=bf16(relu(acc+bias)); MODE 2: Cf+=acc+bias; MODE 3: QKV scatter.
template<int MODE>
__global__ __launch_bounds__(256, 2)
void gemm_bt(const unsigned short* __restrict__ A, const unsigned short* __restrict__ B,
             const float* __restrict__ bias, float* __restrict__ Cf,
             unsigned short* __restrict__ Cb, unsigned short* __restrict__ qkp,
             unsigned short* __restrict__ vtp, int M, int N, int K)
{
  __shared__ unsigned short As[128 * 64];
  __shared__ unsigned short Bs[128 * 64];
  const int tid = threadIdx.x;
  const int w = tid >> 6, lane = tid & 63;
  const int wm = w >> 1, wn = w & 1;
  const int lr = lane & 15, lh = lane >> 4;
  const int m0 = blockIdx.x << 7, n0 = blockIdx.y << 7;
  const int rA = lane >> 3;
  const int cA = (lane & 7) << 3;

  f32x4 acc[4][4];
  #pragma unroll
  for (int i = 0; i < 4; ++i)
    #pragma unroll
    for (int j = 0; j < 4; ++j) acc[i][j] = (f32x4)0.f;

  const int nkt = K >> 6;
  auto stage = [&](int kt){
    #pragma unroll
    for (int c = 0; c < 4; ++c){
      const int r = (c << 5) + (w << 3) + rA;
      gld16(A + (size_t)(m0 + r) * K + (kt << 6) + cA,
            (char*)As + ((c << 5) + (w << 3)) * 128);
      gld16(B + (size_t)(n0 + r) * K + (kt << 6) + cA,
            (char*)Bs + ((c << 5) + (w << 3)) * 128);
    }
  };
  stage(0);
  for (int kt = 0; kt < nkt; ++kt){
    __syncthreads();
    #pragma unroll
    for (int kk = 0; kk < 2; ++kk){
      bfx8 af[4], bg[4];
      #pragma unroll
      for (int i = 0; i < 4; ++i)
        af[i] = *(const bfx8*)(As + ((wm << 6) + (i << 4) + lr) * 64 + (kk << 5) + (lh << 3));
      #pragma unroll
      for (int j = 0; j < 4; ++j)
        bg[j] = *(const bfx8*)(Bs + ((wn << 6) + (j << 4) + lr) * 64 + (kk << 5) + (lh << 3));
      #pragma unroll
      for (int i = 0; i < 4; ++i)
        #pragma unroll
        for (int j = 0; j < 4; ++j)
          acc[i][j] = mfma16(af[i], bg[j], acc[i][j]);
    }
    __syncthreads();
    if (kt + 1 < nkt) stage(kt + 1);
  }
  #pragma unroll
  for (int i = 0; i < 4; ++i){
    const int row = m0 + (wm << 6) + (i << 4) + (lh << 2);
    #pragma unroll
    for (int j = 0; j < 4; ++j){
      const int col = n0 + (wn << 6) + (j << 4) + lr;
      if constexpr (MODE == 1){
        const float bv = bias ? bias[col] : 0.f;
        #pragma unroll
        for (int r = 0; r < 4; ++r){
          float v = acc[i][j][r] + bv;
          v = fmaxf(v, 0.f);
          Cb[(size_t)(row + r) * N + col] = f2bf(v);
        }
      } else if constexpr (MODE == 2){
        const float bv = bias ? bias[col] : 0.f;
        #pragma unroll
        for (int r = 0; r < 4; ++r)
          Cf[(size_t)(row + r) * N + col] += acc[i][j][r] + bv;
      } else {
        const int br = col / 1536;
        const int rem = col - br * 1536;
        const int p = rem >> 9;
        const int c = rem & 511;
        const float bv = bias ? bias[(size_t)((br << 2) + p) * 512 + c] : 0.f;
        if (p < 2){
          #pragma unroll
          for (int r = 0; r < 4; ++r)
            qkp[((size_t)((br << 1) + p) * 8192 + row + r) * 512 + c] = f2bf(acc[i][j][r] + bv);
        } else {
          const int b_ = row >> 9, s0 = row & 511;
          const int hi = c >> 7, dk = c & 127;
          us4 pk;
          #pragma unroll
          for (int r = 0; r < 4; ++r) pk[r] = f2bf(acc[i][j][r] + bv);
          *(us4*)(vtp + (((size_t)(br * 16 + b_) * 4 + hi) * 128 + dk) * 512 + s0) = pk;
        }
      }
    }
  }
}

// ---------------------------------------------------------------- attention --
// Flash-style, SWAPPED QK^T (q in lane dim): st = mfma(K,Q) puts q=lr, key in
// regs -> register row-reduce + 2 shfl; P store = 2 x ds_write_b64 of cvt_pk
// pairs; lp reduced once in epilogue. K+V triple-buffered, counted vmcnt(2).
__global__ __launch_bounds__(512, 4)
void attn_kernel(const unsigned short* __restrict__ qk, const unsigned short* __restrict__ vt,
                 const unsigned* __restrict__ mp, unsigned short* __restrict__ outp)
{
  __shared__ unsigned short KV[3][8192];   // per buf: K [32][128] | V [128][32]
  __shared__ unsigned short Pl[8][16 * 40];
  __shared__ unsigned Mk[8][16 * 17];
  const int tid = threadIdx.x;
  const int w = tid >> 6, lane = tid & 63;
  const int lr = lane & 15, lh = lane >> 4;
  const int id = blockIdx.x;
  const int wg = (id & 7) * 96 + (id >> 3);          // XCD swizzle (768 = 8*96)
  const int qt = wg & 3, head = wg >> 2;             // 4 q-tiles of 128 rows
  const int br = head >> 6, bh = head & 63;
  const int b = bh >> 2, h = bh & 3;
  const int q0 = (qt << 7) + (w << 4);

  const unsigned short* qbase = qk + ((size_t)(br * 2 + 0) * 8192 + (size_t)b * 512) * 512 + h * 128;
  const unsigned short* kbase = qk + ((size_t)(br * 2 + 1) * 8192 + (size_t)b * 512) * 512 + h * 128;
  const unsigned short* vbase = vt + ((size_t)(br * 16 + b) * 4 + h) * 128 * 512;
  const unsigned* mrow = mp + ((size_t)br * 8192 + (size_t)b * 512 + q0) * 16;

  // per-wave packed-mask fill (wave-local; lgkm-fenced)
  unsigned* mk = Mk[w];
  #pragma unroll
  for (int u = 0; u < 4; ++u){
    const int idx = (lane << 2) + u;
    const int rw = idx >> 4, wd = idx & 15;
    mk[rw * 17 + wd] = mrow[rw * 16 + wd];
  }
  asm volatile("s_waitcnt lgkmcnt(0)" ::: "memory");
  __builtin_amdgcn_sched_barrier(0);

  bfx8 aq[4];
  #pragma unroll
  for (int t = 0; t < 4; ++t)
    aq[t] = *(const bfx8*)(qbase + (size_t)(q0 + lr) * 512 + (t << 5) + (lh << 3));

  // staging geometry (per wave: 1KB of K + 1KB of V per tile)
  const int krow = (w << 2) + (lane >> 4);                 // local K row 0..31
  const int kg = (lane & 15) ^ (krow & 7);
  const int vrow = (w << 4) + (lane >> 2);                 // local V(dk) row 0..127
  const int vg = (lane & 3) ^ ((vrow & 3) ^ ((vrow >> 2) & 3));
  auto stageKt = [&](int kt, int buf){
    gld16(kbase + ((size_t)((kt << 5) + krow) << 9) + (kg << 3),
          (char*)&KV[buf][w << 9]);
    gld16(vbase + ((size_t)vrow << 9) + (kt << 5) + (vg << 3),
          (char*)&KV[buf][4096 + (w << 9)]);
  };

  const float scale = 0.08838834764831845f;  // 1/sqrt(128)
  f32x4 ao[8];
  #pragma unroll
  for (int j = 0; j < 8; ++j) ao[j] = (f32x4)0.f;
  float m = -3e38f;     // running row max, q = lr (replicated across lh groups)
  float lp = 0.f;       // PARTIAL row sum (this lane's lh-group of keys)
  unsigned short* pw = Pl[w];

  stageKt(0, 0); stageKt(1, 1);
  int bcur = 0;
  for (int kt = 0; kt < 16; ++kt){
    if (kt < 15) asm volatile("s_waitcnt vmcnt(2)" ::: "memory");
    else         asm volatile("s_waitcnt vmcnt(0)" ::: "memory");
    BAR();
    if (kt < 14){
      const int bst = (bcur == 0) ? 2 : bcur - 1;   // (kt+2)%3
      stageKt(kt + 2, bst);
    }
    const unsigned short* Kb = &KV[bcur][0];
    const unsigned short* Vb = &KV[bcur][4096];

    // QK^T (SWAPPED): st[j][r] holds S[key=(j<<4)+(lh<<2)+r][q=lr]
    f32x4 st[2];
    const unsigned mword = mk[lr * 17 + kt];
    #pragma unroll
    for (int j = 0; j < 2; ++j){
      const int rk = (j << 4) + lr;
      f32x4 a2 = (f32x4)0.f;
      __builtin_amdgcn_s_setprio(1);
      #pragma unroll
      for (int t = 0; t < 4; ++t){
        const int s = ((t << 2) + lh) ^ (rk & 7);
        bfx8 bk = *(const bfx8*)&Kb[rk * 128 + (s << 3)];
        a2 = mfma16(bk, aq[t], a2);          // A=K, B=Q
      }
      __builtin_amdgcn_s_setprio(0);
      #pragma unroll
      for (int r = 0; r < 4; ++r){
        const int bit = (mword >> ((j << 4) + (lh << 2) + r)) & 1;
        st[j][r] = bit ? -1e9f : a2[r] * scale;
      }
    }

    // row max of this tile: register reduce + cross-lh shfl (2 steps)
    float pmax = fmaxf(fmaxf(fmaxf(st[0][0], st[0][1]), fmaxf(st[0][2], st[0][3])),
                       fmaxf(fmaxf(st[1][0], st[1][1]), fmaxf(st[1][2], st[1][3])));
    pmax = fmaxf(pmax, __shfl_xor(pmax, 16, 64));
    pmax = fmaxf(pmax, __shfl_xor(pmax, 32, 64));
    // deferred rescale (THR=8)
    if (__any(pmax > m + 8.f)){
      const float mn = fmaxf(m, pmax);
      const float f = __expf(m - mn);
      m = mn; lp *= f;
      float fr[4];
      #pragma unroll
      for (int r = 0; r < 4; ++r) fr[r] = __shfl(f, (lh << 2) + r, 64);
      #pragma unroll
      for (int j = 0; j < 8; ++j)
        #pragma unroll
        for (int r = 0; r < 4; ++r) ao[j][r] *= fr[r];
    }
    // P = exp(S-m); accumulate partial lp; pack to LDS (2 x b64 per lane)
    #pragma unroll
    for (int j = 0; j < 2; ++j){
      #pragma unroll
      for (int r = 0; r < 4; ++r){
        st[j][r] = __expf(st[j][r] - m);
        lp += st[j][r];
      }
      uint2 pk;
      pk.x = cvt_pk_bf16(st[j][0], st[j][1]);
      pk.y = cvt_pk_bf16(st[j][2], st[j][3]);
      *(uint2*)(pw + lr * 40 + (j << 4) + (lh << 2)) = pk;
    }
    asm volatile("s_waitcnt lgkmcnt(0)" ::: "memory");
    __builtin_amdgcn_sched_barrier(0);
    bfx8 pa = *(const bfx8*)(pw + lr * 40 + (lh << 3));

    // PV for this tile
    __builtin_amdgcn_s_setprio(1);
    #pragma unroll
    for (int j = 0; j < 8; ++j){
      const int dd = (j << 4) + lr;
      const int s = lh ^ ((dd & 3) ^ ((dd >> 2) & 3));
      bfx8 bv = *(const bfx8*)&Vb[dd * 32 + (s << 3)];
      ao[j] = mfma16(pa, bv, ao[j]);
    }
    __builtin_amdgcn_s_setprio(0);
    asm volatile("" ::: "memory");
    bcur = (bcur == 2) ? 0 : bcur + 1;
  }

  // epilogue: total lp across lh groups, normalize (factors to q-in-register)
  lp += __shfl_xor(lp, 16, 64);
  lp += __shfl_xor(lp, 32, 64);
  const float rcp = 1.f / lp;
  float linv[4];
  #pragma unroll
  for (int r = 0; r < 4; ++r) linv[r] = __shfl(rcp, (lh << 2) + r, 64);
  const size_t obase = (size_t)(b * 512) * 1536 + br * 512 + h * 128;
  #pragma unroll
  for (int j = 0; j < 8; ++j){
    const int d = (j << 4) + lr;
    #pragma unroll
    for (int r = 0; r < 4; ++r){
      const int q = q0 + (lh << 2) + r;
      outp[obase + (size_t)q * 1536 + d] = f2bf(ao[j][r] * linv[r]);
    }
  }
}

// ---------------------------------------------------------------- out3 -------
__global__ __launch_bounds__(256, 4)
void out3_kernel(const unsigned short* __restrict__ t2, const float* __restrict__ w,
                 const float* __restrict__ b2, float* __restrict__ outp)
{
  const int row = (blockIdx.x << 2) + (threadIdx.x >> 6);
  const int lane = threadIdx.x & 63;
  const unsigned short* rp = t2 + (size_t)row * 256 + (lane << 2);
  float a0 = 0.f, a1 = 0.f;
  #pragma unroll
  for (int k = 0; k < 4; ++k){
    const float v = bf2f(rp[k]);
    const int kk = (lane << 2) + k;
    a0 += v * w[kk * 2 + 0];
    a1 += v * w[kk * 2 + 1];
  }
  #pragma unroll
  for (int s = 1; s < 64; s <<= 1){
    a0 += __shfl_xor(a0, s, 64);
    a1 += __shfl_xor(a1, s, 64);
  }
  if (lane == 0){
    outp[(size_t)row * 2 + 0] = a0 + b2[0];
    outp[(size_t)row * 2 + 1] = a1 + b2[1];
  }
}

// ---------------------------------------------------------------- launch -----
extern "C" void kernel_launch(void* const* d_in, const int* in_sizes, int n_in,
                              void* d_out, int out_size, void* d_ws, size_t ws_size,
                              hipStream_t stream)
{
  const float* x      = (const float*)d_in[0];
  const float* cond   = (const float*)d_in[1];
  const int*   mdoor  = (const int*)d_in[2];
  const int*   mself  = (const int*)d_in[3];
  const int*   mgen   = (const int*)d_in[4];
  const float* attn_w = (const float*)d_in[5];
  const float* attn_b = (const float*)d_in[6];
  const float* ff_w1  = (const float*)d_in[7];
  const float* ff_b1  = (const float*)d_in[8];
  const float* ff_w2  = (const float*)d_in[9];
  const float* ff_b2  = (const float*)d_in[10];
  const float* in_w   = (const float*)d_in[11];
  const float* in_b   = (const float*)d_in[12];
  const float* cond_w = (const float*)d_in[13];
  const float* cond_b = (const float*)d_in[14];
  const float* out1_w = (const float*)d_in[15];
  const float* out1_b = (const float*)d_in[16];
  const float* out2_w = (const float*)d_in[17];
  const float* out2_b = (const float*)d_in[18];
  const float* out3_w = (const float*)d_in[19];
  const float* out3_b = (const float*)d_in[20];

  char* p = (char*)d_ws;
  auto carve = [&](size_t bytes) -> char* {
    char* r = p; p += (bytes + 255) & ~(size_t)255; return r;
  };
  float*          h    = (float*)carve(8192ull * 512 * 4);
  unsigned short* h2   = (unsigned short*)carve(8192ull * 512 * 2);
  unsigned short* bqkv = (unsigned short*)carve(4ull * 4608 * 512 * 2);
  unsigned short* bout = (unsigned short*)carve(4ull * 512 * 1536 * 2);
  unsigned short* bff1 = (unsigned short*)carve(4ull * 1024 * 512 * 2);
  unsigned short* bff2 = (unsigned short*)carve(4ull * 512 * 1024 * 2);
  unsigned short* bo1  = (unsigned short*)carve(512ull * 512 * 2);
  unsigned short* bo2  = (unsigned short*)carve(256ull * 512 * 2);
  unsigned short* qkb  = (unsigned short*)carve(6ull * 8192 * 512 * 2);
  unsigned short* vtb  = (unsigned short*)carve(3ull * 16 * 4 * 128 * 512 * 2);
  unsigned short* att  = (unsigned short*)carve(8192ull * 1536 * 2);
  unsigned short* t    = (unsigned short*)carve(8192ull * 1024 * 2);
  unsigned short* t2   = (unsigned short*)carve(8192ull * 256 * 2);
  unsigned long long* mpk = (unsigned long long*)carve(24576ull * 8 * 8);
  float* outf = (float*)d_out;

  wconv_kernel<<<dim3(16, 16, 58), 256, 0, stream>>>(attn_w, ff_w1, ff_w2, out1_w, out2_w,
                                                     bqkv, bout, bff1, bff2, bo1, bo2);
  mpack_kernel<<<dim3(6144), 256, 0, stream>>>(mdoor, mself, mgen, mpk);
  embed_kernel<<<dim3(1024), 256, 0, stream>>>(x, cond, in_w, in_b, cond_w, cond_b, h);
  for (int l = 0; l < 4; ++l){
    inorm_kernel<<<dim3(2048), 256, 0, stream>>>(h, h2);
    gemm_bt<3><<<dim3(64, 36), 256, 0, stream>>>(h2, bqkv + (size_t)l * 4608 * 512,
        attn_b + (size_t)l * 6144, nullptr, nullptr, qkb, vtb, 8192, 4608, 512);
    attn_kernel<<<dim3(768), 512, 0, stream>>>(qkb, vtb, (const unsigned*)mpk, att);
    gemm_bt<2><<<dim3(64, 4), 256, 0, stream>>>(att, bout + (size_t)l * 512 * 1536,
        nullptr, h, nullptr, nullptr, nullptr, 8192, 512, 1536);
    inorm_kernel<<<dim3(2048), 256, 0, stream>>>(h, h2);
    gemm_bt<1><<<dim3(64, 8), 256, 0, stream>>>(h2, bff1 + (size_t)l * 1024 * 512,
        ff_b1 + (size_t)l * 1024, nullptr, t, nullptr, nullptr, 8192, 1024, 512);
    gemm_bt<2><<<dim3(64, 4), 256, 0, stream>>>(t, bff2 + (size_t)l * 512 * 1024,
        ff_b2 + (size_t)l * 512, h, nullptr, nullptr, nullptr, 8192, 512, 1024);
  }
  f2b_kernel<<<dim3(4096), 256, 0, stream>>>(h, h2, 8192 * 512);
  gemm_bt<1><<<dim3(64, 4), 256, 0, stream>>>(h2, bo1, out1_b, nullptr, att, nullptr, nullptr, 8192, 512, 512);
  gemm_bt<1><<<dim3(64, 2), 256, 0, stream>>>(att, bo2, out2_b, nullptr, t2, nullptr, nullptr, 8192, 256, 512);
  out3_kernel<<<dim3(2048), 256, 0, stream>>>(t2, out3_w, out3_b, outf);
}

// Round 7
// 1145.252 us; speedup vs baseline: 2.2690x; 1.0257x over previous
//
#include <hip/hip_runtime.h>
#include <hip/hip_bf16.h>

#define DEV static __device__ __forceinline__

typedef __attribute__((ext_vector_type(8))) short bfx8;
typedef __attribute__((ext_vector_type(4))) float f32x4;
typedef __attribute__((ext_vector_type(4))) unsigned short us4;

DEV unsigned short f2bf(float f){
  unsigned u = __builtin_bit_cast(unsigned, f);
  u += 0x7fffu + ((u >> 16) & 1u);
  return (unsigned short)(u >> 16);
}
DEV float bf2f(unsigned short h){
  unsigned u = ((unsigned)h) << 16;
  return __builtin_bit_cast(float, u);
}
DEV unsigned cvt_pk_bf16(float lo, float hi){
  unsigned r;
  asm("v_cvt_pk_bf16_f32 %0, %1, %2" : "=v"(r) : "v"(lo), "v"(hi));
  return r;
}
DEV void gld16(const void* g, void* l){
  __builtin_amdgcn_global_load_lds((const __attribute__((address_space(1))) void*)g,
                                   (__attribute__((address_space(3))) void*)l, 16, 0, 0);
}
DEV f32x4 mfma16(bfx8 a, bfx8 b, f32x4 c){
  return __builtin_amdgcn_mfma_f32_16x16x32_bf16(a, b, c, 0, 0, 0);
}

#define BAR() do{ asm volatile("" ::: "memory"); __builtin_amdgcn_s_barrier(); \
                  asm volatile("" ::: "memory"); }while(0)

// ---------------------------------------------------------------- weights ----
__global__ __launch_bounds__(256, 2)
void wconv_kernel(const float* __restrict__ attn_w, const float* __restrict__ ff_w1,
                  const float* __restrict__ ff_w2, const float* __restrict__ out1_w,
                  const float* __restrict__ out2_w,
                  unsigned short* __restrict__ bqkv, unsigned short* __restrict__ bout,
                  unsigned short* __restrict__ bff1, unsigned short* __restrict__ bff2,
                  unsigned short* __restrict__ bo1, unsigned short* __restrict__ bo2)
{
  __shared__ float ts[64][65];
  const int z = blockIdx.z;
  const float* src; unsigned short* dst; int K, N, stride;
  if (z < 48){
    int l = z / 12, br = (z % 12) >> 2, p = z & 3;
    src = attn_w + (size_t)z * 262144; K = 512; N = 512;
    if (p < 3){ dst = bqkv + (size_t)l * 4608 * 512 + (size_t)(br * 3 + p) * 262144; stride = 512; }
    else      { dst = bout + (size_t)l * 512 * 1536 + (size_t)br * 512;              stride = 1536; }
  } else if (z < 52){
    int l = z - 48; src = ff_w1 + (size_t)l * 524288; K = 512; N = 1024;
    dst = bff1 + (size_t)l * 524288; stride = 512;
  } else if (z < 56){
    int l = z - 52; src = ff_w2 + (size_t)l * 524288; K = 1024; N = 512;
    dst = bff2 + (size_t)l * 524288; stride = 1024;
  } else if (z == 56){
    src = out1_w; K = 512; N = 512; dst = bo1; stride = 512;
  } else {
    src = out2_w; K = 512; N = 256; dst = bo2; stride = 512;
  }
  const int n0 = blockIdx.x << 6, k0 = blockIdx.y << 6;
  if (n0 >= N || k0 >= K) return;
  const int tx = threadIdx.x & 63, ty = threadIdx.x >> 6;
  #pragma unroll
  for (int i = 0; i < 16; ++i){
    int row = (ty << 4) + i;
    ts[row][tx] = src[(size_t)(k0 + row) * N + n0 + tx];
  }
  __syncthreads();
  #pragma unroll
  for (int i = 0; i < 16; ++i){
    int row = (ty << 4) + i;
    dst[(size_t)(n0 + row) * stride + k0 + tx] = f2bf(ts[tx][row]);
  }
}

// ---------------------------------------------------------------- mask pack --
__global__ __launch_bounds__(256, 4)
void mpack_kernel(const int* __restrict__ m0, const int* __restrict__ m1,
                  const int* __restrict__ m2, unsigned long long* __restrict__ mp)
{
  const int row = (blockIdx.x << 2) + (threadIdx.x >> 6);
  const int lane = threadIdx.x & 63;
  const int* src = (row < 8192) ? (m0 + (size_t)row * 512)
                 : (row < 16384 ? (m1 + (size_t)(row - 8192) * 512)
                                : (m2 + (size_t)(row - 16384) * 512));
  #pragma unroll
  for (int c = 0; c < 8; ++c){
    const int v = src[(c << 6) + lane];
    const unsigned long long b = __ballot(v != 0);
    if (lane == c) mp[(size_t)row * 8 + c] = b;
  }
}

// ---------------------------------------------------------------- embed ------
__global__ __launch_bounds__(256, 4)
void embed_kernel(const float* __restrict__ x, const float* __restrict__ cond,
                  const float* __restrict__ in_w, const float* __restrict__ in_b,
                  const float* __restrict__ cond_w, const float* __restrict__ cond_b,
                  float* __restrict__ h)
{
  __shared__ float xs[8][18];
  __shared__ float cs[8][89];
  const int m0 = blockIdx.x << 3;
  const int tid = threadIdx.x;
  for (int i = tid; i < 144; i += 256) xs[i / 18][i % 18] = x[(size_t)m0 * 18 + i];
  for (int i = tid; i < 712; i += 256) cs[i / 89][i % 89] = cond[(size_t)m0 * 89 + i];
  __syncthreads();
  #pragma unroll
  for (int hf = 0; hf < 2; ++hf){
    const int c = tid + (hf << 8);
    const float bsum = in_b[c] + cond_b[c];
    float a[8];
    #pragma unroll
    for (int mi = 0; mi < 8; ++mi) a[mi] = bsum;
    #pragma unroll
    for (int k = 0; k < 18; ++k){
      const float wv = in_w[k * 512 + c];
      #pragma unroll
      for (int mi = 0; mi < 8; ++mi) a[mi] += xs[mi][k] * wv;
    }
    for (int k = 0; k < 89; ++k){
      const float wv = cond_w[k * 512 + c];
      #pragma unroll
      for (int mi = 0; mi < 8; ++mi) a[mi] += cs[mi][k] * wv;
    }
    #pragma unroll
    for (int mi = 0; mi < 8; ++mi) h[(size_t)(m0 + mi) * 512 + c] = a[mi];
  }
}

// ---------------------------------------------------------------- inorm ------
__global__ __launch_bounds__(256, 4)
void inorm_kernel(const float* __restrict__ in, unsigned short* __restrict__ ob)
{
  const int wid = (blockIdx.x << 2) + (threadIdx.x >> 6);
  const int lane = threadIdx.x & 63;
  const float* row = in + (size_t)wid * 512;
  const float4 v0 = *(const float4*)(row + (lane << 2));
  const float4 v1 = *(const float4*)(row + 256 + (lane << 2));
  float s = v0.x + v0.y + v0.z + v0.w + v1.x + v1.y + v1.z + v1.w;
  float q = v0.x*v0.x + v0.y*v0.y + v0.z*v0.z + v0.w*v0.w
          + v1.x*v1.x + v1.y*v1.y + v1.z*v1.z + v1.w*v1.w;
  #pragma unroll
  for (int sh = 1; sh < 64; sh <<= 1){
    s += __shfl_xor(s, sh, 64);
    q += __shfl_xor(q, sh, 64);
  }
  const float mean = s * (1.f / 512.f);
  const float var = q * (1.f / 512.f) - mean * mean;
  const float rs = rsqrtf(var + 1e-5f);
  us4 o0, o1;
  o0[0] = f2bf((v0.x - mean) * rs); o0[1] = f2bf((v0.y - mean) * rs);
  o0[2] = f2bf((v0.z - mean) * rs); o0[3] = f2bf((v0.w - mean) * rs);
  o1[0] = f2bf((v1.x - mean) * rs); o1[1] = f2bf((v1.y - mean) * rs);
  o1[2] = f2bf((v1.z - mean) * rs); o1[3] = f2bf((v1.w - mean) * rs);
  *(us4*)(ob + (size_t)wid * 512 + (lane << 2)) = o0;
  *(us4*)(ob + (size_t)wid * 512 + 256 + (lane << 2)) = o1;
}

__global__ void f2b_kernel(const float* __restrict__ in, unsigned short* __restrict__ ob, int n)
{
  const int i = (blockIdx.x * 256 + threadIdx.x) << 2;
  if (i >= n) return;
  const float4 v = *(const float4*)(in + i);
  us4 o; o[0] = f2bf(v.x); o[1] = f2bf(v.y); o[2] = f2bf(v.z); o[3] = f2bf(v.w);
  *(us4*)(ob + i) = o;
}

// ---------------------------------------------------------------- GEMM 128 ---
// 128x128 tile, BK=64, DOUBLE-buffered LDS, stage(kt+1) issued BEFORE
// compute(kt), counted vmcnt(8) + raw barriers, XOR-granule swizzle (2-way),
// setprio around MFMA cluster.
// MODE 1: Cb=bf16(relu(acc+bias)); MODE 2: Cf+=acc+bias; MODE 3: QKV scatter.
template<int MODE>
__global__ __launch_bounds__(256, 2)
void gemm_bt(const unsigned short* __restrict__ A, const unsigned short* __restrict__ B,
             const float* __restrict__ bias, float* __restrict__ Cf,
             unsigned short* __restrict__ Cb, unsigned short* __restrict__ qkp,
             unsigned short* __restrict__ vtp, int M, int N, int K)
{
  __shared__ unsigned short As[2][128 * 64];
  __shared__ unsigned short Bs[2][128 * 64];
  const int tid = threadIdx.x;
  const int w = tid >> 6, lane = tid & 63;
  const int wm = w >> 1, wn = w & 1;
  const int lr = lane & 15, lh = lane >> 4;
  const int m0 = blockIdx.x << 7, n0 = blockIdx.y << 7;
  const int rA = lane >> 3;
  const int gsw = ((lane & 7) ^ rA) << 3;   // swizzled source granule (elems)

  f32x4 acc[4][4];
  #pragma unroll
  for (int i = 0; i < 4; ++i)
    #pragma unroll
    for (int j = 0; j < 4; ++j) acc[i][j] = (f32x4)0.f;

  const int nkt = K >> 6;
  // stage one K-tile (64 cols) of A and B into buf; LDS dest linear,
  // global source granule pre-swizzled: LDS[r][g] = G[r][g ^ (r&7)]
  auto stage = [&](int kt, int buf){
    #pragma unroll
    for (int c = 0; c < 4; ++c){
      const int r = (c << 5) + (w << 3) + rA;
      gld16(A + (size_t)(m0 + r) * K + (kt << 6) + gsw,
            (char*)As[buf] + ((c << 5) + (w << 3)) * 128);
      gld16(B + (size_t)(n0 + r) * K + (kt << 6) + gsw,
            (char*)Bs[buf] + ((c << 5) + (w << 3)) * 128);
    }
  };
  stage(0, 0);
  for (int kt = 0; kt < nkt; ++kt){
    const int buf = kt & 1;
    if (kt + 1 < nkt){
      stage(kt + 1, buf ^ 1);                       // issue early: overlaps compute
      asm volatile("s_waitcnt vmcnt(8)" ::: "memory");  // drain stage(kt) only
    } else {
      asm volatile("s_waitcnt vmcnt(0)" ::: "memory");
    }
    BAR();                                          // all waves' tile-kt data landed
    #pragma unroll
    for (int kk = 0; kk < 2; ++kk){
      bfx8 af[4], bg[4];
      #pragma unroll
      for (int i = 0; i < 4; ++i){
        const int ra = (wm << 6) + (i << 4) + lr;
        af[i] = *(const bfx8*)(As[buf] + ra * 64 + ((((kk << 2) + lh) ^ (lr & 7)) << 3));
      }
      #pragma unroll
      for (int j = 0; j < 4; ++j){
        const int rb = (wn << 6) + (j << 4) + lr;
        bg[j] = *(const bfx8*)(Bs[buf] + rb * 64 + ((((kk << 2) + lh) ^ (lr & 7)) << 3));
      }
      __builtin_amdgcn_s_setprio(1);
      #pragma unroll
      for (int i = 0; i < 4; ++i)
        #pragma unroll
        for (int j = 0; j < 4; ++j)
          acc[i][j] = mfma16(af[i], bg[j], acc[i][j]);
      __builtin_amdgcn_s_setprio(0);
    }
    BAR();                                          // readers done before overwrite
  }
  #pragma unroll
  for (int i = 0; i < 4; ++i){
    const int row = m0 + (wm << 6) + (i << 4) + (lh << 2);
    #pragma unroll
    for (int j = 0; j < 4; ++j){
      const int col = n0 + (wn << 6) + (j << 4) + lr;
      if constexpr (MODE == 1){
        const float bv = bias ? bias[col] : 0.f;
        #pragma unroll
        for (int r = 0; r < 4; ++r){
          float v = acc[i][j][r] + bv;
          v = fmaxf(v, 0.f);
          Cb[(size_t)(row + r) * N + col] = f2bf(v);
        }
      } else if constexpr (MODE == 2){
        const float bv = bias ? bias[col] : 0.f;
        #pragma unroll
        for (int r = 0; r < 4; ++r)
          Cf[(size_t)(row + r) * N + col] += acc[i][j][r] + bv;
      } else {
        const int br = col / 1536;
        const int rem = col - br * 1536;
        const int p = rem >> 9;
        const int c = rem & 511;
        const float bv = bias ? bias[(size_t)((br << 2) + p) * 512 + c] : 0.f;
        if (p < 2){
          #pragma unroll
          for (int r = 0; r < 4; ++r)
            qkp[((size_t)((br << 1) + p) * 8192 + row + r) * 512 + c] = f2bf(acc[i][j][r] + bv);
        } else {
          const int b_ = row >> 9, s0 = row & 511;
          const int hi = c >> 7, dk = c & 127;
          us4 pk;
          #pragma unroll
          for (int r = 0; r < 4; ++r) pk[r] = f2bf(acc[i][j][r] + bv);
          *(us4*)(vtp + (((size_t)(br * 16 + b_) * 4 + hi) * 128 + dk) * 512 + s0) = pk;
        }
      }
    }
  }
}

// ---------------------------------------------------------------- attention --
// Flash-style, SWAPPED QK^T (q in lane dim): st = mfma(K,Q) puts q=lr, key in
// regs -> register row-reduce + 2 shfl; P store = 2 x ds_write_b64 of cvt_pk
// pairs; lp reduced once in epilogue. K+V triple-buffered, counted vmcnt(2).
__global__ __launch_bounds__(512, 4)
void attn_kernel(const unsigned short* __restrict__ qk, const unsigned short* __restrict__ vt,
                 const unsigned* __restrict__ mp, unsigned short* __restrict__ outp)
{
  __shared__ unsigned short KV[3][8192];   // per buf: K [32][128] | V [128][32]
  __shared__ unsigned short Pl[8][16 * 40];
  __shared__ unsigned Mk[8][16 * 17];
  const int tid = threadIdx.x;
  const int w = tid >> 6, lane = tid & 63;
  const int lr = lane & 15, lh = lane >> 4;
  const int id = blockIdx.x;
  const int wg = (id & 7) * 96 + (id >> 3);          // XCD swizzle (768 = 8*96)
  const int qt = wg & 3, head = wg >> 2;             // 4 q-tiles of 128 rows
  const int br = head >> 6, bh = head & 63;
  const int b = bh >> 2, h = bh & 3;
  const int q0 = (qt << 7) + (w << 4);

  const unsigned short* qbase = qk + ((size_t)(br * 2 + 0) * 8192 + (size_t)b * 512) * 512 + h * 128;
  const unsigned short* kbase = qk + ((size_t)(br * 2 + 1) * 8192 + (size_t)b * 512) * 512 + h * 128;
  const unsigned short* vbase = vt + ((size_t)(br * 16 + b) * 4 + h) * 128 * 512;
  const unsigned* mrow = mp + ((size_t)br * 8192 + (size_t)b * 512 + q0) * 16;

  // per-wave packed-mask fill (wave-local; lgkm-fenced)
  unsigned* mk = Mk[w];
  #pragma unroll
  for (int u = 0; u < 4; ++u){
    const int idx = (lane << 2) + u;
    const int rw = idx >> 4, wd = idx & 15;
    mk[rw * 17 + wd] = mrow[rw * 16 + wd];
  }
  asm volatile("s_waitcnt lgkmcnt(0)" ::: "memory");
  __builtin_amdgcn_sched_barrier(0);

  bfx8 aq[4];
  #pragma unroll
  for (int t = 0; t < 4; ++t)
    aq[t] = *(const bfx8*)(qbase + (size_t)(q0 + lr) * 512 + (t << 5) + (lh << 3));

  // staging geometry (per wave: 1KB of K + 1KB of V per tile)
  const int krow = (w << 2) + (lane >> 4);                 // local K row 0..31
  const int kg = (lane & 15) ^ (krow & 7);
  const int vrow = (w << 4) + (lane >> 2);                 // local V(dk) row 0..127
  const int vg = (lane & 3) ^ ((vrow & 3) ^ ((vrow >> 2) & 3));
  auto stageKt = [&](int kt, int buf){
    gld16(kbase + ((size_t)((kt << 5) + krow) << 9) + (kg << 3),
          (char*)&KV[buf][w << 9]);
    gld16(vbase + ((size_t)vrow << 9) + (kt << 5) + (vg << 3),
          (char*)&KV[buf][4096 + (w << 9)]);
  };

  const float scale = 0.08838834764831845f;  // 1/sqrt(128)
  f32x4 ao[8];
  #pragma unroll
  for (int j = 0; j < 8; ++j) ao[j] = (f32x4)0.f;
  float m = -3e38f;     // running row max, q = lr (replicated across lh groups)
  float lp = 0.f;       // PARTIAL row sum (this lane's lh-group of keys)
  unsigned short* pw = Pl[w];

  stageKt(0, 0); stageKt(1, 1);
  int bcur = 0;
  for (int kt = 0; kt < 16; ++kt){
    if (kt < 15) asm volatile("s_waitcnt vmcnt(2)" ::: "memory");
    else         asm volatile("s_waitcnt vmcnt(0)" ::: "memory");
    BAR();
    if (kt < 14){
      const int bst = (bcur == 0) ? 2 : bcur - 1;   // (kt+2)%3
      stageKt(kt + 2, bst);
    }
    const unsigned short* Kb = &KV[bcur][0];
    const unsigned short* Vb = &KV[bcur][4096];

    // QK^T (SWAPPED): st[j][r] holds S[key=(j<<4)+(lh<<2)+r][q=lr]
    f32x4 st[2];
    const unsigned mword = mk[lr * 17 + kt];
    #pragma unroll
    for (int j = 0; j < 2; ++j){
      const int rk = (j << 4) + lr;
      f32x4 a2 = (f32x4)0.f;
      __builtin_amdgcn_s_setprio(1);
      #pragma unroll
      for (int t = 0; t < 4; ++t){
        const int s = ((t << 2) + lh) ^ (rk & 7);
        bfx8 bk = *(const bfx8*)&Kb[rk * 128 + (s << 3)];
        a2 = mfma16(bk, aq[t], a2);          // A=K, B=Q
      }
      __builtin_amdgcn_s_setprio(0);
      #pragma unroll
      for (int r = 0; r < 4; ++r){
        const int bit = (mword >> ((j << 4) + (lh << 2) + r)) & 1;
        st[j][r] = bit ? -1e9f : a2[r] * scale;
      }
    }

    // row max of this tile: register reduce + cross-lh shfl (2 steps)
    float pmax = fmaxf(fmaxf(fmaxf(st[0][0], st[0][1]), fmaxf(st[0][2], st[0][3])),
                       fmaxf(fmaxf(st[1][0], st[1][1]), fmaxf(st[1][2], st[1][3])));
    pmax = fmaxf(pmax, __shfl_xor(pmax, 16, 64));
    pmax = fmaxf(pmax, __shfl_xor(pmax, 32, 64));
    // deferred rescale (THR=8)
    if (__any(pmax > m + 8.f)){
      const float mn = fmaxf(m, pmax);
      const float f = __expf(m - mn);
      m = mn; lp *= f;
      float fr[4];
      #pragma unroll
      for (int r = 0; r < 4; ++r) fr[r] = __shfl(f, (lh << 2) + r, 64);
      #pragma unroll
      for (int j = 0; j < 8; ++j)
        #pragma unroll
        for (int r = 0; r < 4; ++r) ao[j][r] *= fr[r];
    }
    // P = exp(S-m); accumulate partial lp; pack to LDS (2 x b64 per lane)
    #pragma unroll
    for (int j = 0; j < 2; ++j){
      #pragma unroll
      for (int r = 0; r < 4; ++r){
        st[j][r] = __expf(st[j][r] - m);
        lp += st[j][r];
      }
      uint2 pk;
      pk.x = cvt_pk_bf16(st[j][0], st[j][1]);
      pk.y = cvt_pk_bf16(st[j][2], st[j][3]);
      *(uint2*)(pw + lr * 40 + (j << 4) + (lh << 2)) = pk;
    }
    asm volatile("s_waitcnt lgkmcnt(0)" ::: "memory");
    __builtin_amdgcn_sched_barrier(0);
    bfx8 pa = *(const bfx8*)(pw + lr * 40 + (lh << 3));

    // PV for this tile
    __builtin_amdgcn_s_setprio(1);
    #pragma unroll
    for (int j = 0; j < 8; ++j){
      const int dd = (j << 4) + lr;
      const int s = lh ^ ((dd & 3) ^ ((dd >> 2) & 3));
      bfx8 bv = *(const bfx8*)&Vb[dd * 32 + (s << 3)];
      ao[j] = mfma16(pa, bv, ao[j]);
    }
    __builtin_amdgcn_s_setprio(0);
    asm volatile("" ::: "memory");
    bcur = (bcur == 2) ? 0 : bcur + 1;
  }

  // epilogue: total lp across lh groups, normalize (factors to q-in-register)
  lp += __shfl_xor(lp, 16, 64);
  lp += __shfl_xor(lp, 32, 64);
  const float rcp = 1.f / lp;
  float linv[4];
  #pragma unroll
  for (int r = 0; r < 4; ++r) linv[r] = __shfl(rcp, (lh << 2) + r, 64);
  const size_t obase = (size_t)(b * 512) * 1536 + br * 512 + h * 128;
  #pragma unroll
  for (int j = 0; j < 8; ++j){
    const int d = (j << 4) + lr;
    #pragma unroll
    for (int r = 0; r < 4; ++r){
      const int q = q0 + (lh << 2) + r;
      outp[obase + (size_t)q * 1536 + d] = f2bf(ao[j][r] * linv[r]);
    }
  }
}

// ---------------------------------------------------------------- out3 -------
__global__ __launch_bounds__(256, 4)
void out3_kernel(const unsigned short* __restrict__ t2, const float* __restrict__ w,
                 const float* __restrict__ b2, float* __restrict__ outp)
{
  const int row = (blockIdx.x << 2) + (threadIdx.x >> 6);
  const int lane = threadIdx.x & 63;
  const unsigned short* rp = t2 + (size_t)row * 256 + (lane << 2);
  float a0 = 0.f, a1 = 0.f;
  #pragma unroll
  for (int k = 0; k < 4; ++k){
    const float v = bf2f(rp[k]);
    const int kk = (lane << 2) + k;
    a0 += v * w[kk * 2 + 0];
    a1 += v * w[kk * 2 + 1];
  }
  #pragma unroll
  for (int s = 1; s < 64; s <<= 1){
    a0 += __shfl_xor(a0, s, 64);
    a1 += __shfl_xor(a1, s, 64);
  }
  if (lane == 0){
    outp[(size_t)row * 2 + 0] = a0 + b2[0];
    outp[(size_t)row * 2 + 1] = a1 + b2[1];
  }
}

// ---------------------------------------------------------------- launch -----
extern "C" void kernel_launch(void* const* d_in, const int* in_sizes, int n_in,
                              void* d_out, int out_size, void* d_ws, size_t ws_size,
                              hipStream_t stream)
{
  const float* x      = (const float*)d_in[0];
  const float* cond   = (const float*)d_in[1];
  const int*   mdoor  = (const int*)d_in[2];
  const int*   mself  = (const int*)d_in[3];
  const int*   mgen   = (const int*)d_in[4];
  const float* attn_w = (const float*)d_in[5];
  const float* attn_b = (const float*)d_in[6];
  const float* ff_w1  = (const float*)d_in[7];
  const float* ff_b1  = (const float*)d_in[8];
  const float* ff_w2  = (const float*)d_in[9];
  const float* ff_b2  = (const float*)d_in[10];
  const float* in_w   = (const float*)d_in[11];
  const float* in_b   = (const float*)d_in[12];
  const float* cond_w = (const float*)d_in[13];
  const float* cond_b = (const float*)d_in[14];
  const float* out1_w = (const float*)d_in[15];
  const float* out1_b = (const float*)d_in[16];
  const float* out2_w = (const float*)d_in[17];
  const float* out2_b = (const float*)d_in[18];
  const float* out3_w = (const float*)d_in[19];
  const float* out3_b = (const float*)d_in[20];

  char* p = (char*)d_ws;
  auto carve = [&](size_t bytes) -> char* {
    char* r = p; p += (bytes + 255) & ~(size_t)255; return r;
  };
  float*          h    = (float*)carve(8192ull * 512 * 4);
  unsigned short* h2   = (unsigned short*)carve(8192ull * 512 * 2);
  unsigned short* bqkv = (unsigned short*)carve(4ull * 4608 * 512 * 2);
  unsigned short* bout = (unsigned short*)carve(4ull * 512 * 1536 * 2);
  unsigned short* bff1 = (unsigned short*)carve(4ull * 1024 * 512 * 2);
  unsigned short* bff2 = (unsigned short*)carve(4ull * 512 * 1024 * 2);
  unsigned short* bo1  = (unsigned short*)carve(512ull * 512 * 2);
  unsigned short* bo2  = (unsigned short*)carve(256ull * 512 * 2);
  unsigned short* qkb  = (unsigned short*)carve(6ull * 8192 * 512 * 2);
  unsigned short* vtb  = (unsigned short*)carve(3ull * 16 * 4 * 128 * 512 * 2);
  unsigned short* att  = (unsigned short*)carve(8192ull * 1536 * 2);
  unsigned short* t    = (unsigned short*)carve(8192ull * 1024 * 2);
  unsigned short* t2   = (unsigned short*)carve(8192ull * 256 * 2);
  unsigned long long* mpk = (unsigned long long*)carve(24576ull * 8 * 8);
  float* outf = (float*)d_out;

  wconv_kernel<<<dim3(16, 16, 58), 256, 0, stream>>>(attn_w, ff_w1, ff_w2, out1_w, out2_w,
                                                     bqkv, bout, bff1, bff2, bo1, bo2);
  mpack_kernel<<<dim3(6144), 256, 0, stream>>>(mdoor, mself, mgen, mpk);
  embed_kernel<<<dim3(1024), 256, 0, stream>>>(x, cond, in_w, in_b, cond_w, cond_b, h);
  for (int l = 0; l < 4; ++l){
    inorm_kernel<<<dim3(2048), 256, 0, stream>>>(h, h2);
    gemm_bt<3><<<dim3(64, 36), 256, 0, stream>>>(h2, bqkv + (size_t)l * 4608 * 512,
        attn_b + (size_t)l * 6144, nullptr, nullptr, qkb, vtb, 8192, 4608, 512);
    attn_kernel<<<dim3(768), 512, 0, stream>>>(qkb, vtb, (const unsigned*)mpk, att);
    gemm_bt<2><<<dim3(64, 4), 256, 0, stream>>>(att, bout + (size_t)l * 512 * 1536,
        nullptr, h, nullptr, nullptr, nullptr, 8192, 512, 1536);
    inorm_kernel<<<dim3(2048), 256, 0, stream>>>(h, h2);
    gemm_bt<1><<<dim3(64, 8), 256, 0, stream>>>(h2, bff1 + (size_t)l * 1024 * 512,
        ff_b1 + (size_t)l * 1024, nullptr, t, nullptr, nullptr, 8192, 1024, 512);
    gemm_bt<2><<<dim3(64, 4), 256, 0, stream>>>(t, bff2 + (size_t)l * 512 * 1024,
        ff_b2 + (size_t)l * 512, h, nullptr, nullptr, nullptr, 8192, 512, 1024);
  }
  f2b_kernel<<<dim3(4096), 256, 0, stream>>>(h, h2, 8192 * 512);
  gemm_bt<1><<<dim3(64, 4), 256, 0, stream>>>(h2, bo1, out1_b, nullptr, att, nullptr, nullptr, 8192, 512, 512);
  gemm_bt<1><<<dim3(64, 2), 256, 0, stream>>>(att, bo2, out2_b, nullptr, t2, nullptr, nullptr, 8192, 256, 512);
  out3_kernel<<<dim3(2048), 256, 0, stream>>>(t2, out3_w, out3_b, outf);
}